// Round 1
// baseline (2545.684 us; speedup 1.0000x reference)
//
#include <hip/hip_runtime.h>
#include <math.h>

#define B_   192
#define C_   512
#define HW_  784
#define TPK  23          // int(784*0.03)

__device__ __forceinline__ float sigf(float x) {
    return 1.0f / (1.0f + __expf(-x));
}

// ---------------------------------------------------------------- evmean
// one wave per (b,c) row of 784; evmean[b,c] = mean_p ev[b,c,p]
__global__ void k_evmean(const float* __restrict__ ev, float* __restrict__ evmean) {
    int row  = blockIdx.x * 4 + (threadIdx.x >> 6);
    int lane = threadIdx.x & 63;
    const float4* s4 = (const float4*)(ev + (size_t)row * HW_);
    float s = 0.f;
    for (int i = lane; i < HW_ / 4; i += 64) {
        float4 v = s4[i];
        s += v.x + v.y + v.z + v.w;
    }
    for (int off = 32; off > 0; off >>= 1) s += __shfl_down(s, off, 64);
    if (lane == 0) evmean[row] = s * (1.0f / HW_);
}

// ---------------------------------------------------------------- ind_vec + iv_norm
// block b: ind_vec[b,o] = sum_c Wv[o,c]*evmean[b,c]; iv_norm = l2norm(ind_vec)
__global__ void k_indvec(const float* __restrict__ evmean, const float* __restrict__ Wv,
                         float* __restrict__ ind_vec, float* __restrict__ iv_norm) {
    __shared__ float evm[C_];
    __shared__ float outv[C_];
    __shared__ float red[256];
    int b = blockIdx.x, tid = threadIdx.x;
    evm[tid]       = evmean[b * C_ + tid];
    evm[tid + 256] = evmean[b * C_ + tid + 256];
    __syncthreads();
    float ss = 0.f;
    for (int r = 0; r < 2; r++) {
        int o = tid + r * 256;
        const float* wr = Wv + (size_t)o * C_;
        float acc = 0.f;
        for (int c = 0; c < C_; c++) acc = fmaf(wr[c], evm[c], acc);
        outv[o] = acc;
        ss += acc * acc;
    }
    red[tid] = ss; __syncthreads();
    for (int s = 128; s > 0; s >>= 1) { if (tid < s) red[tid] += red[tid + s]; __syncthreads(); }
    float rn = 1.0f / fmaxf(sqrtf(red[0]), 1e-12f);
    for (int r = 0; r < 2; r++) {
        int o = tid + r * 256;
        ind_vec[b * C_ + o] = outv[o];
        iv_norm[b * C_ + o] = outv[o] * rn;
    }
}

// ---------------------------------------------------------------- U = iv_norm @ Wv
// U[d,c] = sum_o iv_norm[d,o] * Wv[o,c]
__global__ void k_U(const float* __restrict__ iv_norm, const float* __restrict__ Wv,
                    float* __restrict__ U) {
    __shared__ float ivn[C_];
    int d = blockIdx.x, tid = threadIdx.x;
    ivn[tid]       = iv_norm[d * C_ + tid];
    ivn[tid + 256] = iv_norm[d * C_ + tid + 256];
    __syncthreads();
    for (int r = 0; r < 2; r++) {
        int c = tid + r * 256;
        float acc = 0.f;
        for (int o = 0; o < C_; o++) acc = fmaf(Wv[(size_t)o * C_ + c], ivn[o], acc);
        U[d * C_ + c] = acc;
    }
}

// ---------------------------------------------------------------- fa = relu(ea@Wa1^T)@Wa2^T
__global__ void k_fa(const float* __restrict__ ea, const float* __restrict__ Wa1,
                     const float* __restrict__ Wa2, float* __restrict__ fa) {
    __shared__ float ear[2048];
    __shared__ float hs[C_];
    int b = blockIdx.x, tid = threadIdx.x;
    for (int i = tid; i < 2048; i += 256) ear[i] = ea[b * 2048 + i];
    __syncthreads();
    for (int r = 0; r < 2; r++) {
        int o = tid + r * 256;
        const float* wr = Wa1 + (size_t)o * 2048;
        float acc = 0.f;
        for (int k = 0; k < 2048; k++) acc = fmaf(wr[k], ear[k], acc);
        hs[o] = fmaxf(acc, 0.f);
    }
    __syncthreads();
    for (int r = 0; r < 2; r++) {
        int o = tid + r * 256;
        const float* wr = Wa2 + (size_t)o * C_;
        float acc = 0.f;
        for (int k = 0; k < C_; k++) acc = fmaf(wr[k], hs[k], acc);
        fa[b * C_ + o] = acc;
    }
}

// ---------------------------------------------------------------- big fused GEMM
// per b: M = [Wv; U] (704x512) @ ev[b] (512x784)
// rows 0..511  -> n2[b,p] += sum_o M[o,p]^2   (atomic partial per o-tile)
// rows 512..703 -> T[bl,d,p] = M[512+d, p]
#define BO 64
#define BP 64
#define BK 16
#define NTILE 143   // 13 p-tiles * 11 o-tiles

__global__ __launch_bounds__(256)
void k_gemm(const float* __restrict__ ev, const float* __restrict__ Wv,
            const float* __restrict__ U, float* __restrict__ n2,
            float* __restrict__ T, int b0, int nb) {
    // XCD-aware swizzle: all tiles of one b stay on one XCD (L2 keeps ev[b] resident)
    int id   = blockIdx.x;
    int xcd  = id & 7;
    int slot = id >> 3;
    int tile = slot % NTILE;
    int bl   = (slot / NTILE) * 8 + xcd;
    if (bl >= nb) return;
    int po = tile % 13, oo = tile / 13;
    int p0 = po * BP, o0 = oo * BO;
    int b  = b0 + bl;

    __shared__ float As[BK][BO];   // [k][o]
    __shared__ float Bs[BK][BP];   // [k][p]
    __shared__ float red[16][64];

    int tid = threadIdx.x;
    int tx = tid & 15, ty = tid >> 4;
    int a_row = tid >> 2, a_c4 = tid & 3;     // A loader: 64 rows x 4 float4
    int b_row = tid >> 4, b_c4 = tid & 15;    // B loader: 16 rows x 16 float4

    const float* Asrc;
    {
        int grow = o0 + a_row;
        Asrc = (grow < 512) ? (Wv + (size_t)grow * C_) : (U + (size_t)(grow - 512) * C_);
    }
    const float* Bsrc = ev + (size_t)b * C_ * HW_;

    int  pcol   = p0 + b_c4 * 4;
    bool bvalid = (pcol + 3) < HW_;

    float acc[4][4];
#pragma unroll
    for (int i = 0; i < 4; i++)
#pragma unroll
        for (int j = 0; j < 4; j++) acc[i][j] = 0.f;

    for (int k0 = 0; k0 < C_; k0 += BK) {
        float4 av = *(const float4*)(Asrc + k0 + a_c4 * 4);
        As[a_c4 * 4 + 0][a_row] = av.x;
        As[a_c4 * 4 + 1][a_row] = av.y;
        As[a_c4 * 4 + 2][a_row] = av.z;
        As[a_c4 * 4 + 3][a_row] = av.w;
        float4 bv = make_float4(0.f, 0.f, 0.f, 0.f);
        if (bvalid) bv = *(const float4*)(Bsrc + (size_t)(k0 + b_row) * HW_ + pcol);
        Bs[b_row][b_c4 * 4 + 0] = bv.x;
        Bs[b_row][b_c4 * 4 + 1] = bv.y;
        Bs[b_row][b_c4 * 4 + 2] = bv.z;
        Bs[b_row][b_c4 * 4 + 3] = bv.w;
        __syncthreads();
#pragma unroll
        for (int kk = 0; kk < BK; kk++) {
            float a_[4], bb[4];
#pragma unroll
            for (int i = 0; i < 4; i++) a_[i] = As[kk][ty * 4 + i];
#pragma unroll
            for (int j = 0; j < 4; j++) bb[j] = Bs[kk][tx * 4 + j];
#pragma unroll
            for (int i = 0; i < 4; i++)
#pragma unroll
                for (int j = 0; j < 4; j++)
                    acc[i][j] = fmaf(a_[i], bb[j], acc[i][j]);
        }
        __syncthreads();
    }

    if (o0 < 512) {
#pragma unroll
        for (int j = 0; j < 4; j++) {
            float s = acc[0][j]*acc[0][j] + acc[1][j]*acc[1][j] +
                      acc[2][j]*acc[2][j] + acc[3][j]*acc[3][j];
            red[ty][tx * 4 + j] = s;
        }
        __syncthreads();
        if (tid < 64) {
            float t = 0.f;
#pragma unroll
            for (int r = 0; r < 16; r++) t += red[r][tid];
            int p = p0 + tid;
            if (p < HW_) atomicAdd(&n2[b * HW_ + p], t);
        }
    } else {
        int dbase = o0 - 512;
        if (bvalid) {
#pragma unroll
            for (int i = 0; i < 4; i++) {
                int d = dbase + ty * 4 + i;
                float4 v = make_float4(acc[i][0], acc[i][1], acc[i][2], acc[i][3]);
                *(float4*)(T + ((size_t)bl * B_ + d) * HW_ + pcol) = v;
            }
        }
    }
}

// ---------------------------------------------------------------- top-k pooling per (b,d)
__global__ __launch_bounds__(256)
void k_pool(const float* __restrict__ T, const float* __restrict__ n2,
            float* __restrict__ SP, float* __restrict__ SN, int b0) {
    __shared__ float sv[HW_];
    __shared__ float buf[1024];
    __shared__ float red[4][4];
    int d = blockIdx.x, bl = blockIdx.y, b = b0 + bl;
    int tid = threadIdx.x;
    const float* Trow = T + ((size_t)bl * B_ + d) * HW_;
    for (int p = tid; p < 1024; p += 256) {
        float s = -INFINITY;
        if (p < HW_) {
            float nv = fmaxf(sqrtf(n2[b * HW_ + p]), 1e-12f);
            s = Trow[p] / nv;
            sv[p] = s;
        }
        buf[p] = s;
    }
    // bitonic ascending sort of 1024 (-inf pads sink to front)
    for (int k = 2; k <= 1024; k <<= 1) {
        for (int j = k >> 1; j > 0; j >>= 1) {
            __syncthreads();
            for (int t = tid; t < 1024; t += 256) {
                int ixj = t ^ j;
                if (ixj > t) {
                    float a = buf[t], c = buf[ixj];
                    bool up = ((t & k) == 0);
                    if ((a > c) == up) { buf[t] = c; buf[ixj] = a; }
                }
            }
        }
    }
    __syncthreads();
    float thrp = buf[1024 - TPK];                 // TPK-th largest
    float thrn = buf[1024 - HW_ + TPK - 1];       // TPK-th smallest
    const float its = 1.0f / 0.03f;
    float spn = 0, spd = 0, snn = 0, snd = 0;
    for (int p = tid; p < HW_; p += 256) {
        float s  = sv[p];
        float mp = sigf((s - thrp) * its);
        float mn = sigf(-(s - thrn) * its);
        spn += s * mp; spd += mp;
        snn += s * mn; snd += mn;
    }
    int lane = tid & 63, w = tid >> 6;
    for (int off = 32; off > 0; off >>= 1) {
        spn += __shfl_down(spn, off, 64);
        spd += __shfl_down(spd, off, 64);
        snn += __shfl_down(snn, off, 64);
        snd += __shfl_down(snd, off, 64);
    }
    if (lane == 0) { red[w][0] = spn; red[w][1] = spd; red[w][2] = snn; red[w][3] = snd; }
    __syncthreads();
    if (tid == 0) {
        spn = red[0][0] + red[1][0] + red[2][0] + red[3][0];
        spd = red[0][1] + red[1][1] + red[2][1] + red[3][1];
        snn = red[0][2] + red[1][2] + red[2][2] + red[3][2];
        snd = red[0][3] + red[1][3] + red[2][3] + red[3][3];
        SP[b * B_ + d] = spn / spd;
        SN[b * B_ + d] = snn / snd;
    }
}

// ---------------------------------------------------------------- CE losses (rows of logits1 & logits2)
__global__ void k_loss12(const float* __restrict__ SP, const float* __restrict__ SN,
                         float* __restrict__ acc) {
    __shared__ float red[128];
    int i = blockIdx.x, tid = threadIdx.x;
    const float itc = 1.0f / 0.07f;
    for (int phase = 0; phase < 2; phase++) {
        float mx = -INFINITY;
        for (int j = tid; j < 2 * B_; j += 128) {
            float v;
            if (phase == 0) v = (j < B_ ? SP[i * B_ + j] : SN[i * B_ + (j - B_)]);
            else            v = (j < B_ ? SP[j * B_ + i] : SN[(j - B_) * B_ + i]);
            mx = fmaxf(mx, v * itc);
        }
        red[tid] = mx; __syncthreads();
        for (int s = 64; s > 0; s >>= 1) { if (tid < s) red[tid] = fmaxf(red[tid], red[tid + s]); __syncthreads(); }
        mx = red[0]; __syncthreads();
        float se = 0.f;
        for (int j = tid; j < 2 * B_; j += 128) {
            float v;
            if (phase == 0) v = (j < B_ ? SP[i * B_ + j] : SN[i * B_ + (j - B_)]);
            else            v = (j < B_ ? SP[j * B_ + i] : SN[(j - B_) * B_ + i]);
            se += __expf(v * itc - mx);
        }
        red[tid] = se; __syncthreads();
        for (int s = 64; s > 0; s >>= 1) { if (tid < s) red[tid] += red[tid + s]; __syncthreads(); }
        if (tid == 0) {
            float lse = logf(red[0]) + mx;
            atomicAdd(&acc[phase], lse - SP[i * B_ + i] * itc);
        }
        __syncthreads();
    }
}

// ---------------------------------------------------------------- dist losses
__global__ void k_dist(const float* __restrict__ ind_vec, const float* __restrict__ iv_norm,
                       const float* __restrict__ fa, float* __restrict__ rowsum,
                       float* __restrict__ colsum) {
    __shared__ float ivr[C_], ivnr[C_];
    __shared__ float red[256];
    int i = blockIdx.x, tid = threadIdx.x;
    ivr[tid]        = ind_vec[i * C_ + tid];
    ivr[tid + 256]  = ind_vec[i * C_ + tid + 256];
    ivnr[tid]       = iv_norm[i * C_ + tid];
    ivnr[tid + 256] = iv_norm[i * C_ + tid + 256];
    __syncthreads();
    float val = 0.f;
    int j = tid;
    if (j < B_) {
        float raw = 0.f, vv = 0.f;
        const float* faj  = fa + (size_t)j * C_;
        const float* ivnj = iv_norm + (size_t)j * C_;
        for (int c = 0; c < C_; c++) {
            float dfc = ivr[c] - faj[c] + 1e-6f;
            raw = fmaf(dfc, dfc, raw);
            vv  = fmaf(ivnr[c], ivnj[c], vv);
        }
        val = (i == j) ? raw : raw * vv * (1.0f / 191.0f);
        atomicAdd(&colsum[j], val);
    }
    red[tid] = val; __syncthreads();
    for (int s = 128; s > 0; s >>= 1) { if (tid < s) red[tid] += red[tid + s]; __syncthreads(); }
    if (tid == 0) rowsum[i] = red[0];
}

// ---------------------------------------------------------------- final scalar assembly
__global__ void k_final(const float* __restrict__ acc, const float* __restrict__ rowsum,
                        const float* __restrict__ colsum, float* __restrict__ out) {
    __shared__ float red[256];
    int tid = threadIdx.x;
    float v3 = (tid < B_) ? fmaxf(rowsum[tid] + 0.6f, 0.f) : 0.f;
    float v4 = (tid < B_) ? fmaxf(colsum[tid] + 0.6f, 0.f) : 0.f;
    red[tid] = v3; __syncthreads();
    for (int s = 128; s > 0; s >>= 1) { if (tid < s) red[tid] += red[tid + s]; __syncthreads(); }
    float l3 = red[0] / B_;
    __syncthreads();
    red[tid] = v4; __syncthreads();
    for (int s = 128; s > 0; s >>= 1) { if (tid < s) red[tid] += red[tid + s]; __syncthreads(); }
    float l4 = red[0] / B_;
    if (tid == 0) {
        out[0] = 0.5f * (acc[0] + acc[1]) / B_;
        out[1] = 0.5f * (l3 + l4);
    }
}

extern "C" void kernel_launch(void* const* d_in, const int* in_sizes, int n_in,
                              void* d_out, int out_size, void* d_ws, size_t ws_size,
                              hipStream_t stream) {
    const float* ev  = (const float*)d_in[0];
    const float* ea  = (const float*)d_in[1];
    const float* Wv  = (const float*)d_in[2];
    const float* Wa1 = (const float*)d_in[3];
    const float* Wa2 = (const float*)d_in[4];
    float* out = (float*)d_out;
    float* ws  = (float*)d_ws;

    size_t off = 0;
    float* evmean  = ws + off; off += B_ * C_;
    float* ind_vec = ws + off; off += B_ * C_;
    float* iv_norm = ws + off; off += B_ * C_;
    float* Ub      = ws + off; off += B_ * C_;
    float* fa      = ws + off; off += B_ * C_;
    float* n2      = ws + off; off += B_ * HW_;
    float* SPb     = ws + off; off += B_ * B_;
    float* SNb     = ws + off; off += B_ * B_;
    float* accb    = ws + off; off += 16;
    float* rowsum  = ws + off; off += B_;
    float* colsum  = ws + off; off += B_ + 16;
    float* Tb      = ws + off;

    size_t perB   = (size_t)B_ * HW_;
    size_t remain = ws_size / 4 > off ? ws_size / 4 - off : 0;
    int chunk = (int)(remain / perB);
    if (chunk > B_) chunk = B_;
    if (chunk < 1) chunk = 1;

    hipMemsetAsync(n2,     0, B_ * HW_ * sizeof(float), stream);
    hipMemsetAsync(accb,   0, 2 * sizeof(float), stream);
    hipMemsetAsync(colsum, 0, B_ * sizeof(float), stream);

    k_evmean<<<B_ * C_ / 4, 256, 0, stream>>>(ev, evmean);
    k_indvec<<<B_, 256, 0, stream>>>(evmean, Wv, ind_vec, iv_norm);
    k_U<<<B_, 256, 0, stream>>>(iv_norm, Wv, Ub);
    k_fa<<<B_, 256, 0, stream>>>(ea, Wa1, Wa2, fa);

    for (int b0 = 0; b0 < B_; b0 += chunk) {
        int nb  = (B_ - b0 < chunk) ? (B_ - b0) : chunk;
        int nb8 = (nb + 7) / 8;
        int grid = nb8 * NTILE * 8;
        k_gemm<<<grid, 256, 0, stream>>>(ev, Wv, Ub, n2, Tb, b0, nb);
        dim3 g2(B_, nb);
        k_pool<<<g2, 256, 0, stream>>>(Tb, n2, SPb, SNb, b0);
    }

    k_loss12<<<B_, 128, 0, stream>>>(SPb, SNb, accb);
    k_dist<<<B_, 256, 0, stream>>>(ind_vec, iv_norm, fa, rowsum, colsum);
    k_final<<<1, 256, 0, stream>>>(accb, rowsum, colsum, out);
}

// Round 2
// 757.374 us; speedup vs baseline: 3.3612x; 3.3612x over previous
//
#include <hip/hip_runtime.h>
#include <math.h>

#define B_   192
#define C_   512
#define HW_  784
#define TPK  23          // int(784*0.03)
#define PPAD 896         // 7 p-tiles of 128

typedef __attribute__((ext_vector_type(8))) short s8bf;
typedef __attribute__((ext_vector_type(4))) float f4;

__device__ __forceinline__ float sigf(float x) {
    return 1.0f / (1.0f + __expf(-x));
}
__device__ __forceinline__ unsigned short f2bf(float f) {
    unsigned u = __float_as_uint(f);
    unsigned r = u + 0x7FFFu + ((u >> 16) & 1u);
    return (unsigned short)(r >> 16);
}
__device__ __forceinline__ float bf2f(unsigned short u) {
    return __uint_as_float(((unsigned)u) << 16);
}
__device__ __forceinline__ void gld16(const unsigned short* g, unsigned short* l) {
    __builtin_amdgcn_global_load_lds((const __attribute__((address_space(1))) unsigned int*)g,
                                     (__attribute__((address_space(3))) unsigned int*)l, 16, 0, 0);
}

// ---------------------------------------------------------------- evmean
__global__ void k_evmean(const float* __restrict__ ev, float* __restrict__ evmean) {
    int row  = blockIdx.x * 4 + (threadIdx.x >> 6);
    int lane = threadIdx.x & 63;
    const float4* s4 = (const float4*)(ev + (size_t)row * HW_);
    float s = 0.f;
    for (int i = lane; i < HW_ / 4; i += 64) {
        float4 v = s4[i];
        s += v.x + v.y + v.z + v.w;
    }
    for (int off = 32; off > 0; off >>= 1) s += __shfl_down(s, off, 64);
    if (lane == 0) evmean[row] = s * (1.0f / HW_);
}

// ---------------------------------------------------------------- ind_vec + iv_norm (fp32 exact)
__global__ void k_indvec(const float* __restrict__ evmean, const float* __restrict__ Wv,
                         float* __restrict__ ind_vec, float* __restrict__ iv_norm) {
    __shared__ float evm[C_];
    __shared__ float outv[C_];
    __shared__ float red[256];
    int b = blockIdx.x, tid = threadIdx.x;
    evm[tid]       = evmean[b * C_ + tid];
    evm[tid + 256] = evmean[b * C_ + tid + 256];
    __syncthreads();
    float ss = 0.f;
    for (int r = 0; r < 2; r++) {
        int o = tid + r * 256;
        const float* wr = Wv + (size_t)o * C_;
        float acc = 0.f;
        for (int c = 0; c < C_; c++) acc = fmaf(wr[c], evm[c], acc);
        outv[o] = acc;
        ss += acc * acc;
    }
    red[tid] = ss; __syncthreads();
    for (int s = 128; s > 0; s >>= 1) { if (tid < s) red[tid] += red[tid + s]; __syncthreads(); }
    float rn = 1.0f / fmaxf(sqrtf(red[0]), 1e-12f);
    for (int r = 0; r < 2; r++) {
        int o = tid + r * 256;
        ind_vec[b * C_ + o] = outv[o];
        iv_norm[b * C_ + o] = outv[o] * rn;
    }
}

// ---------------------------------------------------------------- U = iv_norm @ Wv
__global__ void k_U(const float* __restrict__ iv_norm, const float* __restrict__ Wv,
                    float* __restrict__ U) {
    __shared__ float ivn[C_];
    int d = blockIdx.x, tid = threadIdx.x;
    ivn[tid]       = iv_norm[d * C_ + tid];
    ivn[tid + 256] = iv_norm[d * C_ + tid + 256];
    __syncthreads();
    for (int r = 0; r < 2; r++) {
        int c = tid + r * 256;
        float acc = 0.f;
        for (int o = 0; o < C_; o++) acc = fmaf(Wv[(size_t)o * C_ + c], ivn[o], acc);
        U[d * C_ + c] = acc;
    }
}

// ---------------------------------------------------------------- fa = relu(ea@Wa1^T)@Wa2^T
__global__ void k_fa(const float* __restrict__ ea, const float* __restrict__ Wa1,
                     const float* __restrict__ Wa2, float* __restrict__ fa) {
    __shared__ float ear[2048];
    __shared__ float hs[C_];
    int b = blockIdx.x, tid = threadIdx.x;
    for (int i = tid; i < 2048; i += 256) ear[i] = ea[b * 2048 + i];
    __syncthreads();
    for (int r = 0; r < 2; r++) {
        int o = tid + r * 256;
        const float* wr = Wa1 + (size_t)o * 2048;
        float acc = 0.f;
        for (int k = 0; k < 2048; k++) acc = fmaf(wr[k], ear[k], acc);
        hs[o] = fmaxf(acc, 0.f);
    }
    __syncthreads();
    for (int r = 0; r < 2; r++) {
        int o = tid + r * 256;
        const float* wr = Wa2 + (size_t)o * C_;
        float acc = 0.f;
        for (int k = 0; k < C_; k++) acc = fmaf(wr[k], hs[k], acc);
        fa[b * C_ + o] = acc;
    }
}

// ---------------------------------------------------------------- Abf = bf16([Wv; U; 0pad]) [768][512]
__global__ void k_prepA(const float* __restrict__ Wv, const float* __restrict__ U,
                        unsigned short* __restrict__ Abf) {
    int r = blockIdx.x, tid = threadIdx.x;
    for (int i = 0; i < 2; i++) {
        int c = tid + i * 256;
        float v = 0.f;
        if (r < 512) v = Wv[(size_t)r * C_ + c];
        else if (r < 704) v = U[(size_t)(r - 512) * C_ + c];
        Abf[(size_t)r * C_ + c] = f2bf(v);
    }
}

// ---------------------------------------------------------------- ev[b][c][p] fp32 -> evT[bl][p][c] bf16 (p padded to 896, zeros)
__global__ void k_transpose(const float* __restrict__ ev, unsigned short* __restrict__ evT,
                            int b0) {
    __shared__ float t32[32][33];
    int bl = blockIdx.z, b = b0 + bl;
    int c0 = blockIdx.y * 32, p0 = blockIdx.x * 32;
    int t = threadIdx.x;
    int lr = t >> 3, lc = t & 7;
    float4 v = make_float4(0.f, 0.f, 0.f, 0.f);
    int p = p0 + lc * 4;
    const float* src = ev + ((size_t)b * C_ + c0 + lr) * HW_;
    if (p + 3 < HW_) v = *(const float4*)(src + p);
    else { for (int j = 0; j < 4; j++) if (p + j < HW_) ((float*)&v)[j] = src[p + j]; }
    t32[lr][lc * 4 + 0] = v.x; t32[lr][lc * 4 + 1] = v.y;
    t32[lr][lc * 4 + 2] = v.z; t32[lr][lc * 4 + 3] = v.w;
    __syncthreads();
    ushort4 o;
    o.x = f2bf(t32[lc * 4 + 0][lr]);
    o.y = f2bf(t32[lc * 4 + 1][lr]);
    o.z = f2bf(t32[lc * 4 + 2][lr]);
    o.w = f2bf(t32[lc * 4 + 3][lr]);
    *(ushort4*)(evT + ((size_t)bl * PPAD + p0 + lr) * C_ + c0 + lc * 4) = o;
}

// ---------------------------------------------------------------- MFMA GEMM: [Wv;U](704x512) @ ev[b](512x784)
// tiles 128x128, BK=32, 4 waves 2x2, wave 64x64 = 4x4 frags of 16x16x32
__global__ __launch_bounds__(256)
void k_gemm(const unsigned short* __restrict__ Abf, const unsigned short* __restrict__ evT,
            float* __restrict__ n2, unsigned short* __restrict__ Tb, int b0, int nb) {
    __shared__ unsigned short As[2][4096];   // [128][32]
    __shared__ unsigned short Bs[2][4096];   // [128][32]
    __shared__ float red[8][128];

    int id = blockIdx.x;
    int xcd = id & 7, slot = id >> 3;
    int S = (nb * 42 + 7) >> 3;
    int w = xcd * S + slot;
    if (w >= nb * 42) return;
    int bl = w / 42, rem = w % 42;
    int pt = rem / 6, ot = rem % 6;
    int o0 = ot * 128, p0 = pt * 128;

    int tid = threadIdx.x;
    int wid = tid >> 6, lane = tid & 63;
    int wy = wid >> 1, wx = wid & 1;
    int l15 = lane & 15, l4 = lane >> 4;

    const unsigned short* Ag = Abf + ((size_t)o0 + (tid >> 2)) * C_ + (tid & 3) * 8;
    const unsigned short* Bg = evT + ((size_t)bl * PPAD + p0 + (tid >> 2)) * C_ + (tid & 3) * 8;
    int lds_off = wid * 512 + lane * 8;      // ushort elements; = linear tid*16 bytes

    f4 acc[4][4] = {};
    int cur = 0;

#define STAGE(buf, k0) do { \
    gld16(Ag + (k0),             &As[buf][0] + lds_off); \
    gld16(Ag + (k0) + 64 * C_,   &As[buf][2048] + lds_off); \
    gld16(Bg + (k0),             &Bs[buf][0] + lds_off); \
    gld16(Bg + (k0) + 64 * C_,   &Bs[buf][2048] + lds_off); \
} while (0)

    STAGE(0, 0);
    __syncthreads();
    for (int t = 0; t < 16; ++t) {
        if (t < 15) STAGE(cur ^ 1, (t + 1) * 32);
        const s8bf* Ar = (const s8bf*)&As[cur][0];
        const s8bf* Br = (const s8bf*)&Bs[cur][0];
        s8bf a[4], b[4];
#pragma unroll
        for (int mi = 0; mi < 4; mi++) a[mi] = Ar[(wy * 64 + mi * 16 + l15) * 4 + l4];
#pragma unroll
        for (int ni = 0; ni < 4; ni++) b[ni] = Br[(wx * 64 + ni * 16 + l15) * 4 + l4];
#pragma unroll
        for (int mi = 0; mi < 4; mi++)
#pragma unroll
            for (int ni = 0; ni < 4; ni++)
                acc[mi][ni] = __builtin_amdgcn_mfma_f32_16x16x32_bf16(a[mi], b[ni], acc[mi][ni], 0, 0, 0);
        __syncthreads();
        cur ^= 1;
    }
#undef STAGE

    if (ot < 4) {
        // norm tiles: n2[b,p] += sum_o acc^2
#pragma unroll
        for (int ni = 0; ni < 4; ni++) {
            float s = 0.f;
#pragma unroll
            for (int mi = 0; mi < 4; mi++)
#pragma unroll
                for (int r = 0; r < 4; r++) { float x = acc[mi][ni][r]; s = fmaf(x, x, s); }
            red[wy * 4 + l4][wx * 64 + ni * 16 + l15] = s;
        }
        __syncthreads();
        if (tid < 128) {
            float s = 0.f;
#pragma unroll
            for (int q = 0; q < 8; q++) s += red[q][tid];
            int p = p0 + tid;
            if (p < HW_) atomicAdd(&n2[(size_t)(b0 + bl) * HW_ + p], s);
        }
    } else {
        int dbase = o0 - 512 + wy * 64;
#pragma unroll
        for (int mi = 0; mi < 4; mi++)
#pragma unroll
            for (int r = 0; r < 4; r++) {
                int dd = dbase + mi * 16 + l4 * 4 + r;
                if (dd < B_) {
                    size_t rowoff = ((size_t)bl * B_ + dd) * HW_;
#pragma unroll
                    for (int ni = 0; ni < 4; ni++) {
                        int p = p0 + wx * 64 + ni * 16 + l15;
                        if (p < HW_) Tb[rowoff + p] = f2bf(acc[mi][ni][r]);
                    }
                }
            }
    }
}

// ---------------------------------------------------------------- invn[b,p] = 1/max(sqrt(n2),1e-12)
__global__ void k_invn(const float* __restrict__ n2, float* __restrict__ invn, int b0, int n) {
    int i = blockIdx.x * 256 + threadIdx.x;
    if (i >= n) return;
    size_t idx = (size_t)b0 * HW_ + i;
    invn[idx] = 1.0f / fmaxf(sqrtf(n2[idx]), 1e-12f);
}

// ---------------------------------------------------------------- pool: wave per (b,d); bisection top-k
__global__ __launch_bounds__(256)
void k_pool(const unsigned short* __restrict__ T, const float* __restrict__ invn,
            float* __restrict__ SP, float* __restrict__ SN, int b0) {
    int tid = threadIdx.x;
    int wv = tid >> 6, lane = tid & 63;
    int d = blockIdx.x * 4 + wv;
    int bl = blockIdx.y, b = b0 + bl;
    const unsigned short* Trow = T + ((size_t)bl * B_ + d) * HW_;
    const float* nrow = invn + (size_t)b * HW_;
    float sv[13];
#pragma unroll
    for (int i = 0; i < 12; i++) {
        int p = lane + i * 64;
        sv[i] = bf2f(Trow[p]) * nrow[p];
    }
    {
        int p = lane + 768;
        sv[12] = (p < HW_) ? bf2f(Trow[p]) * nrow[p] : __uint_as_float(0x7FC00000u); // NaN pad
    }
    float lo = -1.2f, hi = 1.2f;
    for (int it = 0; it < 26; ++it) {
        float mid = 0.5f * (lo + hi);
        int c = 0;
#pragma unroll
        for (int i = 0; i < 13; i++) c += __popcll(__ballot(sv[i] >= mid));
        if (c >= TPK) lo = mid; else hi = mid;
    }
    float thrp = lo;
    lo = -1.2f; hi = 1.2f;
    for (int it = 0; it < 26; ++it) {
        float mid = 0.5f * (lo + hi);
        int c = 0;
#pragma unroll
        for (int i = 0; i < 13; i++) c += __popcll(__ballot(sv[i] <= mid));
        if (c >= TPK) hi = mid; else lo = mid;
    }
    float thrn = hi;
    const float its = 1.0f / 0.03f;
    float spn = 0.f, spd = 0.f, snn = 0.f, snd = 0.f;
#pragma unroll
    for (int i = 0; i < 13; i++) {
        if (i == 12 && lane >= 16) continue;
        float s = sv[i];
        float mp = sigf((s - thrp) * its);
        float mn = sigf(-(s - thrn) * its);
        spn += s * mp; spd += mp;
        snn += s * mn; snd += mn;
    }
    for (int off = 32; off > 0; off >>= 1) {
        spn += __shfl_down(spn, off, 64);
        spd += __shfl_down(spd, off, 64);
        snn += __shfl_down(snn, off, 64);
        snd += __shfl_down(snd, off, 64);
    }
    if (lane == 0) {
        SP[b * B_ + d] = spn / spd;
        SN[b * B_ + d] = snn / snd;
    }
}

// ---------------------------------------------------------------- CE losses
__global__ void k_loss12(const float* __restrict__ SP, const float* __restrict__ SN,
                         float* __restrict__ acc) {
    __shared__ float red[128];
    int i = blockIdx.x, tid = threadIdx.x;
    const float itc = 1.0f / 0.07f;
    for (int phase = 0; phase < 2; phase++) {
        float mx = -INFINITY;
        for (int j = tid; j < 2 * B_; j += 128) {
            float v;
            if (phase == 0) v = (j < B_ ? SP[i * B_ + j] : SN[i * B_ + (j - B_)]);
            else            v = (j < B_ ? SP[j * B_ + i] : SN[(j - B_) * B_ + i]);
            mx = fmaxf(mx, v * itc);
        }
        red[tid] = mx; __syncthreads();
        for (int s = 64; s > 0; s >>= 1) { if (tid < s) red[tid] = fmaxf(red[tid], red[tid + s]); __syncthreads(); }
        mx = red[0]; __syncthreads();
        float se = 0.f;
        for (int j = tid; j < 2 * B_; j += 128) {
            float v;
            if (phase == 0) v = (j < B_ ? SP[i * B_ + j] : SN[i * B_ + (j - B_)]);
            else            v = (j < B_ ? SP[j * B_ + i] : SN[(j - B_) * B_ + i]);
            se += __expf(v * itc - mx);
        }
        red[tid] = se; __syncthreads();
        for (int s = 64; s > 0; s >>= 1) { if (tid < s) red[tid] += red[tid + s]; __syncthreads(); }
        if (tid == 0) {
            float lse = logf(red[0]) + mx;
            atomicAdd(&acc[phase], lse - SP[i * B_ + i] * itc);
        }
        __syncthreads();
    }
}

// ---------------------------------------------------------------- dist losses
__global__ void k_dist(const float* __restrict__ ind_vec, const float* __restrict__ iv_norm,
                       const float* __restrict__ fa, float* __restrict__ rowsum,
                       float* __restrict__ colsum) {
    __shared__ float ivr[C_], ivnr[C_];
    __shared__ float red[256];
    int i = blockIdx.x, tid = threadIdx.x;
    ivr[tid]        = ind_vec[i * C_ + tid];
    ivr[tid + 256]  = ind_vec[i * C_ + tid + 256];
    ivnr[tid]       = iv_norm[i * C_ + tid];
    ivnr[tid + 256] = iv_norm[i * C_ + tid + 256];
    __syncthreads();
    float val = 0.f;
    int j = tid;
    if (j < B_) {
        float raw = 0.f, vv = 0.f;
        const float* faj  = fa + (size_t)j * C_;
        const float* ivnj = iv_norm + (size_t)j * C_;
        for (int c = 0; c < C_; c++) {
            float dfc = ivr[c] - faj[c] + 1e-6f;
            raw = fmaf(dfc, dfc, raw);
            vv  = fmaf(ivnr[c], ivnj[c], vv);
        }
        val = (i == j) ? raw : raw * vv * (1.0f / 191.0f);
        atomicAdd(&colsum[j], val);
    }
    red[tid] = val; __syncthreads();
    for (int s = 128; s > 0; s >>= 1) { if (tid < s) red[tid] += red[tid + s]; __syncthreads(); }
    if (tid == 0) rowsum[i] = red[0];
}

// ---------------------------------------------------------------- final
__global__ void k_final(const float* __restrict__ acc, const float* __restrict__ rowsum,
                        const float* __restrict__ colsum, float* __restrict__ out) {
    __shared__ float red[256];
    int tid = threadIdx.x;
    float v3 = (tid < B_) ? fmaxf(rowsum[tid] + 0.6f, 0.f) : 0.f;
    float v4 = (tid < B_) ? fmaxf(colsum[tid] + 0.6f, 0.f) : 0.f;
    red[tid] = v3; __syncthreads();
    for (int s = 128; s > 0; s >>= 1) { if (tid < s) red[tid] += red[tid + s]; __syncthreads(); }
    float l3 = red[0] / B_;
    __syncthreads();
    red[tid] = v4; __syncthreads();
    for (int s = 128; s > 0; s >>= 1) { if (tid < s) red[tid] += red[tid + s]; __syncthreads(); }
    float l4 = red[0] / B_;
    if (tid == 0) {
        out[0] = 0.5f * (acc[0] + acc[1]) / B_;
        out[1] = 0.5f * (l3 + l4);
    }
}

extern "C" void kernel_launch(void* const* d_in, const int* in_sizes, int n_in,
                              void* d_out, int out_size, void* d_ws, size_t ws_size,
                              hipStream_t stream) {
    const float* ev  = (const float*)d_in[0];
    const float* ea  = (const float*)d_in[1];
    const float* Wv  = (const float*)d_in[2];
    const float* Wa1 = (const float*)d_in[3];
    const float* Wa2 = (const float*)d_in[4];
    float* out = (float*)d_out;
    float* ws  = (float*)d_ws;

    size_t off = 0;
    float* evmean  = ws + off; off += B_ * C_;
    float* ind_vec = ws + off; off += B_ * C_;
    float* iv_norm = ws + off; off += B_ * C_;
    float* Ub      = ws + off; off += B_ * C_;
    float* fa      = ws + off; off += B_ * C_;
    float* n2      = ws + off; off += B_ * HW_;
    float* invn    = ws + off; off += B_ * HW_;
    float* SPb     = ws + off; off += B_ * B_;
    float* SNb     = ws + off; off += B_ * B_;
    float* accb    = ws + off; off += 16;
    float* rowsum  = ws + off; off += B_;
    float* colsum  = ws + off; off += B_ + 16;
    unsigned short* Abf = (unsigned short*)(ws + off); off += 768 * C_ / 2;

    // per-b chunk buffers: evT (PPAD*C_ bf16) + Tb (B_*HW_ bf16)
    size_t perB_f = (size_t)PPAD * C_ / 2 + (size_t)B_ * HW_ / 2;
    size_t avail  = ws_size / 4 > off ? ws_size / 4 - off : 0;
    int chunk = (int)(avail / perB_f);
    if (chunk > B_) chunk = B_;
    if (chunk < 1) chunk = 1;
    unsigned short* evT = (unsigned short*)(ws + off);
    unsigned short* Tb  = evT + (size_t)chunk * PPAD * C_;

    hipMemsetAsync(n2,     0, B_ * HW_ * sizeof(float), stream);
    hipMemsetAsync(accb,   0, 2 * sizeof(float), stream);
    hipMemsetAsync(colsum, 0, B_ * sizeof(float), stream);

    k_evmean<<<B_ * C_ / 4, 256, 0, stream>>>(ev, evmean);
    k_indvec<<<B_, 256, 0, stream>>>(evmean, Wv, ind_vec, iv_norm);
    k_U<<<B_, 256, 0, stream>>>(iv_norm, Wv, Ub);
    k_prepA<<<768, 256, 0, stream>>>(Wv, Ub, Abf);
    k_fa<<<B_, 256, 0, stream>>>(ea, Wa1, Wa2, fa);

    for (int b0 = 0; b0 < B_; b0 += chunk) {
        int nb = (B_ - b0 < chunk) ? (B_ - b0) : chunk;
        dim3 gt(PPAD / 32, C_ / 32, nb);
        k_transpose<<<gt, 256, 0, stream>>>(ev, evT, b0);
        int grid = 8 * ((nb * 42 + 7) / 8);
        k_gemm<<<grid, 256, 0, stream>>>(Abf, evT, n2, Tb, b0, nb);
        int n = nb * HW_;
        k_invn<<<(n + 255) / 256, 256, 0, stream>>>(n2, invn, b0, n);
        dim3 gp(B_ / 4, nb);
        k_pool<<<gp, 256, 0, stream>>>(Tb, invn, SPb, SNb, b0);
    }

    k_loss12<<<B_, 128, 0, stream>>>(SPb, SNb, accb);
    k_dist<<<B_, 256, 0, stream>>>(ind_vec, iv_norm, fa, rowsum, colsum);
    k_final<<<1, 256, 0, stream>>>(accb, rowsum, colsum, out);
}

// Round 3
// 699.901 us; speedup vs baseline: 3.6372x; 1.0821x over previous
//
#include <hip/hip_runtime.h>
#include <math.h>

#define B_   192
#define C_   512
#define HW_  784
#define TPK  23          // int(784*0.03)
#define PPAD 896         // 7 p-tiles of 128

typedef __attribute__((ext_vector_type(8))) short s8bf;
typedef __attribute__((ext_vector_type(4))) float f4;

__device__ __forceinline__ float sigf(float x) {
    return 1.0f / (1.0f + __expf(-x));
}
__device__ __forceinline__ unsigned short f2bf(float f) {
    unsigned u = __float_as_uint(f);
    unsigned r = u + 0x7FFFu + ((u >> 16) & 1u);
    return (unsigned short)(r >> 16);
}
__device__ __forceinline__ float bf2f(unsigned short u) {
    return __uint_as_float(((unsigned)u) << 16);
}
__device__ __forceinline__ void gld16(const unsigned short* g, unsigned short* l) {
    __builtin_amdgcn_global_load_lds((const __attribute__((address_space(1))) unsigned int*)g,
                                     (__attribute__((address_space(3))) unsigned int*)l, 16, 0, 0);
}

// ---------------------------------------------------------------- evmean (fallback only)
__global__ void k_evmean(const float* __restrict__ ev, float* __restrict__ evmean) {
    int row  = blockIdx.x * 4 + (threadIdx.x >> 6);
    int lane = threadIdx.x & 63;
    const float4* s4 = (const float4*)(ev + (size_t)row * HW_);
    float s = 0.f;
    for (int i = lane; i < HW_ / 4; i += 64) {
        float4 v = s4[i];
        s += v.x + v.y + v.z + v.w;
    }
    for (int off = 32; off > 0; off >>= 1) s += __shfl_down(s, off, 64);
    if (lane == 0) evmean[row] = s * (1.0f / HW_);
}

// ---------------------------------------------------------------- ind_vec + iv_norm (fp32 exact)
__global__ void k_indvec(const float* __restrict__ evmean, const float* __restrict__ Wv,
                         float* __restrict__ ind_vec, float* __restrict__ iv_norm) {
    __shared__ float evm[C_];
    __shared__ float outv[C_];
    __shared__ float red[256];
    int b = blockIdx.x, tid = threadIdx.x;
    evm[tid]       = evmean[b * C_ + tid];
    evm[tid + 256] = evmean[b * C_ + tid + 256];
    __syncthreads();
    float ss = 0.f;
    for (int r = 0; r < 2; r++) {
        int o = tid + r * 256;
        const float* wr = Wv + (size_t)o * C_;
        float acc = 0.f;
        for (int c = 0; c < C_; c++) acc = fmaf(wr[c], evm[c], acc);
        outv[o] = acc;
        ss += acc * acc;
    }
    red[tid] = ss; __syncthreads();
    for (int s = 128; s > 0; s >>= 1) { if (tid < s) red[tid] += red[tid + s]; __syncthreads(); }
    float rn = 1.0f / fmaxf(sqrtf(red[0]), 1e-12f);
    for (int r = 0; r < 2; r++) {
        int o = tid + r * 256;
        ind_vec[b * C_ + o] = outv[o];
        iv_norm[b * C_ + o] = outv[o] * rn;
    }
}

// ---------------------------------------------------------------- U = iv_norm @ Wv
__global__ void k_U(const float* __restrict__ iv_norm, const float* __restrict__ Wv,
                    float* __restrict__ U) {
    __shared__ float ivn[C_];
    int d = blockIdx.x, tid = threadIdx.x;
    ivn[tid]       = iv_norm[d * C_ + tid];
    ivn[tid + 256] = iv_norm[d * C_ + tid + 256];
    __syncthreads();
    for (int r = 0; r < 2; r++) {
        int c = tid + r * 256;
        float acc = 0.f;
        for (int o = 0; o < C_; o++) acc = fmaf(Wv[(size_t)o * C_ + c], ivn[o], acc);
        U[d * C_ + c] = acc;
    }
}

// ---------------------------------------------------------------- fa = relu(ea@Wa1^T)@Wa2^T
__global__ void k_fa(const float* __restrict__ ea, const float* __restrict__ Wa1,
                     const float* __restrict__ Wa2, float* __restrict__ fa) {
    __shared__ float ear[2048];
    __shared__ float hs[C_];
    int b = blockIdx.x, tid = threadIdx.x;
    for (int i = tid; i < 2048; i += 256) ear[i] = ea[b * 2048 + i];
    __syncthreads();
    for (int r = 0; r < 2; r++) {
        int o = tid + r * 256;
        const float* wr = Wa1 + (size_t)o * 2048;
        float acc = 0.f;
        for (int k = 0; k < 2048; k++) acc = fmaf(wr[k], ear[k], acc);
        hs[o] = fmaxf(acc, 0.f);
    }
    __syncthreads();
    for (int r = 0; r < 2; r++) {
        int o = tid + r * 256;
        const float* wr = Wa2 + (size_t)o * C_;
        float acc = 0.f;
        for (int k = 0; k < C_; k++) acc = fmaf(wr[k], hs[k], acc);
        fa[b * C_ + o] = acc;
    }
}

// ---------------------------------------------------------------- Abf = bf16([Wv; U; 0pad]) [768][512]
__global__ void k_prepA(const float* __restrict__ Wv, const float* __restrict__ U,
                        unsigned short* __restrict__ Abf) {
    int r = blockIdx.x, tid = threadIdx.x;
    for (int i = 0; i < 2; i++) {
        int c = tid + i * 256;
        float v = 0.f;
        if (r < 512) v = Wv[(size_t)r * C_ + c];
        else if (r < 704) v = U[(size_t)(r - 512) * C_ + c];
        Abf[(size_t)r * C_ + c] = f2bf(v);
    }
}

// ---------------------------------------------------------------- ev[b][c][p] fp32 -> evT[bl][p][c] bf16
// optionally fuses evmean accumulation (doevm: evsum zeroed beforehand, scaled by 1/HW here)
__global__ void k_transpose(const float* __restrict__ ev, unsigned short* __restrict__ evT,
                            float* __restrict__ evsum, int doevm, int b0) {
    __shared__ float t32[32][33];
    int bl = blockIdx.z, b = b0 + bl;
    int c0 = blockIdx.y * 32, p0 = blockIdx.x * 32;
    int t = threadIdx.x;
    int lr = t >> 3, lc = t & 7;
    float4 v = make_float4(0.f, 0.f, 0.f, 0.f);
    int p = p0 + lc * 4;
    const float* src = ev + ((size_t)b * C_ + c0 + lr) * HW_;
    if (p + 3 < HW_) v = *(const float4*)(src + p);
    else { for (int j = 0; j < 4; j++) if (p + j < HW_) ((float*)&v)[j] = src[p + j]; }
    if (doevm) {
        float rs = v.x + v.y + v.z + v.w;
        rs += __shfl_xor(rs, 1, 8);
        rs += __shfl_xor(rs, 2, 8);
        rs += __shfl_xor(rs, 4, 8);
        if (lc == 0) atomicAdd(&evsum[b * C_ + c0 + lr], rs * (1.0f / HW_));
    }
    t32[lr][lc * 4 + 0] = v.x; t32[lr][lc * 4 + 1] = v.y;
    t32[lr][lc * 4 + 2] = v.z; t32[lr][lc * 4 + 3] = v.w;
    __syncthreads();
    ushort4 o;
    o.x = f2bf(t32[lc * 4 + 0][lr]);
    o.y = f2bf(t32[lc * 4 + 1][lr]);
    o.z = f2bf(t32[lc * 4 + 2][lr]);
    o.w = f2bf(t32[lc * 4 + 3][lr]);
    *(ushort4*)(evT + ((size_t)bl * PPAD + p0 + lr) * C_ + c0 + lc * 4) = o;
}

// ---------------------------------------------------------------- MFMA GEMM: [Wv;U](704x512) @ ev[b](512x784)
// tiles 128x128, BK=32, 4 waves 2x2, wave 64x64 = 4x4 frags of 16x16x32
// LDS = exactly 32 KiB (epilogue reduce buffer aliases As) -> 5 blocks/CU
__global__ __launch_bounds__(256)
void k_gemm(const unsigned short* __restrict__ Abf, const unsigned short* __restrict__ evT,
            float* __restrict__ n2, unsigned short* __restrict__ Tb, int b0, int nb) {
    __shared__ unsigned short As[2][4096];   // [128][32]
    __shared__ unsigned short Bs[2][4096];   // [128][32]

    int id = blockIdx.x;
    int xcd = id & 7, slot = id >> 3;
    int S = (nb * 42 + 7) >> 3;
    int w = xcd * S + slot;
    if (w >= nb * 42) return;
    int bl = w / 42, rem = w % 42;
    int pt = rem / 6, ot = rem % 6;
    int o0 = ot * 128, p0 = pt * 128;

    int tid = threadIdx.x;
    int wid = tid >> 6, lane = tid & 63;
    int wy = wid >> 1, wx = wid & 1;
    int l15 = lane & 15, l4 = lane >> 4;

    const unsigned short* Ag = Abf + ((size_t)o0 + (tid >> 2)) * C_ + (tid & 3) * 8;
    const unsigned short* Bg = evT + ((size_t)bl * PPAD + p0 + (tid >> 2)) * C_ + (tid & 3) * 8;
    int lds_off = wid * 512 + lane * 8;      // ushort elements; = linear tid*16 bytes

    f4 acc[4][4] = {};
    int cur = 0;

#define STAGE(buf, k0) do { \
    gld16(Ag + (k0),             &As[buf][0] + lds_off); \
    gld16(Ag + (k0) + 64 * C_,   &As[buf][2048] + lds_off); \
    gld16(Bg + (k0),             &Bs[buf][0] + lds_off); \
    gld16(Bg + (k0) + 64 * C_,   &Bs[buf][2048] + lds_off); \
} while (0)

    STAGE(0, 0);
    __syncthreads();
    for (int t = 0; t < 16; ++t) {
        if (t < 15) STAGE(cur ^ 1, (t + 1) * 32);
        const s8bf* Ar = (const s8bf*)&As[cur][0];
        const s8bf* Br = (const s8bf*)&Bs[cur][0];
        s8bf a[4], b[4];
#pragma unroll
        for (int mi = 0; mi < 4; mi++) a[mi] = Ar[(wy * 64 + mi * 16 + l15) * 4 + l4];
#pragma unroll
        for (int ni = 0; ni < 4; ni++) b[ni] = Br[(wx * 64 + ni * 16 + l15) * 4 + l4];
#pragma unroll
        for (int mi = 0; mi < 4; mi++)
#pragma unroll
            for (int ni = 0; ni < 4; ni++)
                acc[mi][ni] = __builtin_amdgcn_mfma_f32_16x16x32_bf16(a[mi], b[ni], acc[mi][ni], 0, 0, 0);
        __syncthreads();
        cur ^= 1;
    }
#undef STAGE

    if (ot < 4) {
        // norm tiles: n2[b,p] += sum_o acc^2  (reduce buffer aliases dead As)
        float* red = (float*)&As[0][0];
#pragma unroll
        for (int ni = 0; ni < 4; ni++) {
            float s = 0.f;
#pragma unroll
            for (int mi = 0; mi < 4; mi++)
#pragma unroll
                for (int r = 0; r < 4; r++) { float x = acc[mi][ni][r]; s = fmaf(x, x, s); }
            red[(wy * 4 + l4) * 128 + wx * 64 + ni * 16 + l15] = s;
        }
        __syncthreads();
        if (tid < 128) {
            float s = 0.f;
#pragma unroll
            for (int q = 0; q < 8; q++) s += red[q * 128 + tid];
            int p = p0 + tid;
            if (p < HW_) atomicAdd(&n2[(size_t)(b0 + bl) * HW_ + p], s);
        }
    } else {
        int dbase = o0 - 512 + wy * 64;
#pragma unroll
        for (int mi = 0; mi < 4; mi++)
#pragma unroll
            for (int r = 0; r < 4; r++) {
                int dd = dbase + mi * 16 + l4 * 4 + r;
                if (dd < B_) {
                    size_t rowoff = ((size_t)bl * B_ + dd) * HW_;
#pragma unroll
                    for (int ni = 0; ni < 4; ni++) {
                        int p = p0 + wx * 64 + ni * 16 + l15;
                        if (p < HW_) Tb[rowoff + p] = f2bf(acc[mi][ni][r]);
                    }
                }
            }
    }
}

// ---------------------------------------------------------------- invn[b,p] = 1/max(sqrt(n2),1e-12)
__global__ void k_invn(const float* __restrict__ n2, float* __restrict__ invn, int b0, int n) {
    int i = blockIdx.x * 256 + threadIdx.x;
    if (i >= n) return;
    size_t idx = (size_t)b0 * HW_ + i;
    invn[idx] = 1.0f / fmaxf(sqrtf(n2[idx]), 1e-12f);
}

// ---------------------------------------------------------------- pool: wave per (b,d); bisection top-k
__global__ __launch_bounds__(256)
void k_pool(const unsigned short* __restrict__ T, const float* __restrict__ invn,
            float* __restrict__ SP, float* __restrict__ SN, int b0) {
    int tid = threadIdx.x;
    int wv = tid >> 6, lane = tid & 63;
    int d = blockIdx.x * 4 + wv;
    int bl = blockIdx.y, b = b0 + bl;
    const unsigned short* Trow = T + ((size_t)bl * B_ + d) * HW_;
    const float* nrow = invn + (size_t)b * HW_;
    float sv[13];
#pragma unroll
    for (int i = 0; i < 12; i++) {
        int p = lane + i * 64;
        sv[i] = bf2f(Trow[p]) * nrow[p];
    }
    {
        int p = lane + 768;
        sv[12] = (p < HW_) ? bf2f(Trow[p]) * nrow[p] : __uint_as_float(0x7FC00000u); // NaN pad
    }
    // |S| <= 1 + bf16 slop; 22 iters -> ~5e-7 threshold precision (sigmoid scale 0.03)
    float lo = -1.1f, hi = 1.1f;
    for (int it = 0; it < 22; ++it) {
        float mid = 0.5f * (lo + hi);
        int c = 0;
#pragma unroll
        for (int i = 0; i < 13; i++) c += __popcll(__ballot(sv[i] >= mid));
        if (c >= TPK) lo = mid; else hi = mid;
    }
    float thrp = lo;
    lo = -1.1f; hi = 1.1f;
    for (int it = 0; it < 22; ++it) {
        float mid = 0.5f * (lo + hi);
        int c = 0;
#pragma unroll
        for (int i = 0; i < 13; i++) c += __popcll(__ballot(sv[i] <= mid));
        if (c >= TPK) hi = mid; else lo = mid;
    }
    float thrn = hi;
    const float its = 1.0f / 0.03f;
    float spn = 0.f, spd = 0.f, snn = 0.f, snd = 0.f;
#pragma unroll
    for (int i = 0; i < 13; i++) {
        if (i == 12 && lane >= 16) continue;
        float s = sv[i];
        float mp = sigf((s - thrp) * its);
        float mn = sigf(-(s - thrn) * its);
        spn += s * mp; spd += mp;
        snn += s * mn; snd += mn;
    }
    for (int off = 32; off > 0; off >>= 1) {
        spn += __shfl_down(spn, off, 64);
        spd += __shfl_down(spd, off, 64);
        snn += __shfl_down(snn, off, 64);
        snd += __shfl_down(snd, off, 64);
    }
    if (lane == 0) {
        SP[b * B_ + d] = spn / spd;
        SN[b * B_ + d] = snn / snd;
    }
}

// ---------------------------------------------------------------- CE losses
__global__ void k_loss12(const float* __restrict__ SP, const float* __restrict__ SN,
                         float* __restrict__ acc) {
    __shared__ float red[128];
    int i = blockIdx.x, tid = threadIdx.x;
    const float itc = 1.0f / 0.07f;
    for (int phase = 0; phase < 2; phase++) {
        float mx = -INFINITY;
        for (int j = tid; j < 2 * B_; j += 128) {
            float v;
            if (phase == 0) v = (j < B_ ? SP[i * B_ + j] : SN[i * B_ + (j - B_)]);
            else            v = (j < B_ ? SP[j * B_ + i] : SN[(j - B_) * B_ + i]);
            mx = fmaxf(mx, v * itc);
        }
        red[tid] = mx; __syncthreads();
        for (int s = 64; s > 0; s >>= 1) { if (tid < s) red[tid] = fmaxf(red[tid], red[tid + s]); __syncthreads(); }
        mx = red[0]; __syncthreads();
        float se = 0.f;
        for (int j = tid; j < 2 * B_; j += 128) {
            float v;
            if (phase == 0) v = (j < B_ ? SP[i * B_ + j] : SN[i * B_ + (j - B_)]);
            else            v = (j < B_ ? SP[j * B_ + i] : SN[(j - B_) * B_ + i]);
            se += __expf(v * itc - mx);
        }
        red[tid] = se; __syncthreads();
        for (int s = 64; s > 0; s >>= 1) { if (tid < s) red[tid] += red[tid + s]; __syncthreads(); }
        if (tid == 0) {
            float lse = logf(red[0]) + mx;
            atomicAdd(&acc[phase], lse - SP[i * B_ + i] * itc);
        }
        __syncthreads();
    }
}

// ---------------------------------------------------------------- dist losses
__global__ void k_dist(const float* __restrict__ ind_vec, const float* __restrict__ iv_norm,
                       const float* __restrict__ fa, float* __restrict__ rowsum,
                       float* __restrict__ colsum) {
    __shared__ float ivr[C_], ivnr[C_];
    __shared__ float red[256];
    int i = blockIdx.x, tid = threadIdx.x;
    ivr[tid]        = ind_vec[i * C_ + tid];
    ivr[tid + 256]  = ind_vec[i * C_ + tid + 256];
    ivnr[tid]       = iv_norm[i * C_ + tid];
    ivnr[tid + 256] = iv_norm[i * C_ + tid + 256];
    __syncthreads();
    float val = 0.f;
    int j = tid;
    if (j < B_) {
        float raw = 0.f, vv = 0.f;
        const float* faj  = fa + (size_t)j * C_;
        const float* ivnj = iv_norm + (size_t)j * C_;
        for (int c = 0; c < C_; c++) {
            float dfc = ivr[c] - faj[c] + 1e-6f;
            raw = fmaf(dfc, dfc, raw);
            vv  = fmaf(ivnr[c], ivnj[c], vv);
        }
        val = (i == j) ? raw : raw * vv * (1.0f / 191.0f);
        atomicAdd(&colsum[j], val);
    }
    red[tid] = val; __syncthreads();
    for (int s = 128; s > 0; s >>= 1) { if (tid < s) red[tid] += red[tid + s]; __syncthreads(); }
    if (tid == 0) rowsum[i] = red[0];
}

// ---------------------------------------------------------------- final
__global__ void k_final(const float* __restrict__ acc, const float* __restrict__ rowsum,
                        const float* __restrict__ colsum, float* __restrict__ out) {
    __shared__ float red[256];
    int tid = threadIdx.x;
    float v3 = (tid < B_) ? fmaxf(rowsum[tid] + 0.6f, 0.f) : 0.f;
    float v4 = (tid < B_) ? fmaxf(colsum[tid] + 0.6f, 0.f) : 0.f;
    red[tid] = v3; __syncthreads();
    for (int s = 128; s > 0; s >>= 1) { if (tid < s) red[tid] += red[tid + s]; __syncthreads(); }
    float l3 = red[0] / B_;
    __syncthreads();
    red[tid] = v4; __syncthreads();
    for (int s = 128; s > 0; s >>= 1) { if (tid < s) red[tid] += red[tid + s]; __syncthreads(); }
    float l4 = red[0] / B_;
    if (tid == 0) {
        out[0] = 0.5f * (acc[0] + acc[1]) / B_;
        out[1] = 0.5f * (l3 + l4);
    }
}

extern "C" void kernel_launch(void* const* d_in, const int* in_sizes, int n_in,
                              void* d_out, int out_size, void* d_ws, size_t ws_size,
                              hipStream_t stream) {
    const float* ev  = (const float*)d_in[0];
    const float* ea  = (const float*)d_in[1];
    const float* Wv  = (const float*)d_in[2];
    const float* Wa1 = (const float*)d_in[3];
    const float* Wa2 = (const float*)d_in[4];
    float* out = (float*)d_out;
    float* ws  = (float*)d_ws;

    size_t off = 0;
    float* evmean  = ws + off; off += B_ * C_;
    float* ind_vec = ws + off; off += B_ * C_;
    float* iv_norm = ws + off; off += B_ * C_;
    float* Ub      = ws + off; off += B_ * C_;
    float* fa      = ws + off; off += B_ * C_;
    float* n2      = ws + off; off += B_ * HW_;
    float* invn    = ws + off; off += B_ * HW_;
    float* SPb     = ws + off; off += B_ * B_;
    float* SNb     = ws + off; off += B_ * B_;
    float* accb    = ws + off; off += 16;
    float* rowsum  = ws + off; off += B_;
    float* colsum  = ws + off; off += B_ + 16;
    unsigned short* Abf = (unsigned short*)(ws + off); off += 768 * C_ / 2;

    // per-b chunk buffers: evT (PPAD*C_ bf16) + Tb (B_*HW_ bf16)
    size_t perB_f = (size_t)PPAD * C_ / 2 + (size_t)B_ * HW_ / 2;
    size_t avail  = ws_size / 4 > off ? ws_size / 4 - off : 0;
    int chunk = (int)(avail / perB_f);
    if (chunk > B_) chunk = B_;
    if (chunk < 1) chunk = 1;
    unsigned short* evT = (unsigned short*)(ws + off);
    unsigned short* Tb  = evT + (size_t)chunk * PPAD * C_;

    hipMemsetAsync(n2,     0, B_ * HW_ * sizeof(float), stream);
    hipMemsetAsync(accb,   0, 2 * sizeof(float), stream);
    hipMemsetAsync(colsum, 0, B_ * sizeof(float), stream);

    if (chunk >= B_) {
        // full pipeline: single transpose pass computes evmean too (saves one ev read)
        hipMemsetAsync(evmean, 0, B_ * C_ * sizeof(float), stream);
        dim3 gt(PPAD / 32, C_ / 32, B_);
        k_transpose<<<gt, 256, 0, stream>>>(ev, evT, evmean, 1, 0);
        k_indvec<<<B_, 256, 0, stream>>>(evmean, Wv, ind_vec, iv_norm);
        k_U<<<B_, 256, 0, stream>>>(iv_norm, Wv, Ub);
        k_prepA<<<768, 256, 0, stream>>>(Wv, Ub, Abf);
        k_fa<<<B_, 256, 0, stream>>>(ea, Wa1, Wa2, fa);

        int grid = 8 * ((B_ * 42 + 7) / 8);
        k_gemm<<<grid, 256, 0, stream>>>(Abf, evT, n2, Tb, 0, B_);
        int n = B_ * HW_;
        k_invn<<<(n + 255) / 256, 256, 0, stream>>>(n2, invn, 0, n);
        dim3 gp(B_ / 4, B_);
        k_pool<<<gp, 256, 0, stream>>>(Tb, invn, SPb, SNb, 0);
    } else {
        k_evmean<<<B_ * C_ / 4, 256, 0, stream>>>(ev, evmean);
        k_indvec<<<B_, 256, 0, stream>>>(evmean, Wv, ind_vec, iv_norm);
        k_U<<<B_, 256, 0, stream>>>(iv_norm, Wv, Ub);
        k_prepA<<<768, 256, 0, stream>>>(Wv, Ub, Abf);
        k_fa<<<B_, 256, 0, stream>>>(ea, Wa1, Wa2, fa);

        for (int b0 = 0; b0 < B_; b0 += chunk) {
            int nb = (B_ - b0 < chunk) ? (B_ - b0) : chunk;
            dim3 gt(PPAD / 32, C_ / 32, nb);
            k_transpose<<<gt, 256, 0, stream>>>(ev, evT, evmean, 0, b0);
            int grid = 8 * ((nb * 42 + 7) / 8);
            k_gemm<<<grid, 256, 0, stream>>>(Abf, evT, n2, Tb, b0, nb);
            int n = nb * HW_;
            k_invn<<<(n + 255) / 256, 256, 0, stream>>>(n2, invn, b0, n);
            dim3 gp(B_ / 4, nb);
            k_pool<<<gp, 256, 0, stream>>>(Tb, invn, SPb, SNb, b0);
        }
    }

    k_loss12<<<B_, 128, 0, stream>>>(SPb, SNb, accb);
    k_dist<<<B_, 256, 0, stream>>>(ind_vec, iv_norm, fa, rowsum, colsum);
    k_final<<<1, 256, 0, stream>>>(accb, rowsum, colsum, out);
}

// Round 4
// 690.187 us; speedup vs baseline: 3.6884x; 1.0141x over previous
//
#include <hip/hip_runtime.h>
#include <math.h>

#define B_   192
#define C_   512
#define HW_  784
#define TPK  23          // int(784*0.03)
#define PPAD 896         // 7 p-tiles of 128

typedef __attribute__((ext_vector_type(8))) short s8bf;
typedef __attribute__((ext_vector_type(4))) float f4;

__device__ __forceinline__ float sigf(float x) {
    return 1.0f / (1.0f + __expf(-x));
}
__device__ __forceinline__ unsigned short f2bf(float f) {
    unsigned u = __float_as_uint(f);
    unsigned r = u + 0x7FFFu + ((u >> 16) & 1u);
    return (unsigned short)(r >> 16);
}
__device__ __forceinline__ float bf2f(unsigned short u) {
    return __uint_as_float(((unsigned)u) << 16);
}
__device__ __forceinline__ void gld16(const unsigned short* g, unsigned short* l) {
    __builtin_amdgcn_global_load_lds((const __attribute__((address_space(1))) unsigned int*)g,
                                     (__attribute__((address_space(3))) unsigned int*)l, 16, 0, 0);
}

// ---------------------------------------------------------------- evmean (fallback only)
__global__ void k_evmean(const float* __restrict__ ev, float* __restrict__ evmean) {
    int row  = blockIdx.x * 4 + (threadIdx.x >> 6);
    int lane = threadIdx.x & 63;
    const float4* s4 = (const float4*)(ev + (size_t)row * HW_);
    float s = 0.f;
    for (int i = lane; i < HW_ / 4; i += 64) {
        float4 v = s4[i];
        s += v.x + v.y + v.z + v.w;
    }
    for (int off = 32; off > 0; off >>= 1) s += __shfl_down(s, off, 64);
    if (lane == 0) evmean[row] = s * (1.0f / HW_);
}

// ---------------------------------------------------------------- tiled fp32 GEMM
// C[M][N] = op( A[M][K] @ B ),  BKN=0: B[N][K] (B^T form),  BKN=1: B[K][N]
// BM=BN=64, BK=16, 256 threads, 4x4 microtile. M,N multiples of 64; K of 16.
template<int BKN, int RELU>
__global__ __launch_bounds__(256)
void k32(const float* __restrict__ A, const float* __restrict__ B,
         float* __restrict__ C, int M, int N, int K) {
    __shared__ float As[16][68];
    __shared__ float Bs[16][68];
    int m0 = blockIdx.y * 64, n0 = blockIdx.x * 64;
    int tid = threadIdx.x;
    int tx = tid & 15, ty = tid >> 4;
    int r = tid >> 2, c4 = tid & 3;

    float acc[4][4];
#pragma unroll
    for (int i = 0; i < 4; i++)
#pragma unroll
        for (int j = 0; j < 4; j++) acc[i][j] = 0.f;

    for (int k0 = 0; k0 < K; k0 += 16) {
        float4 av = *(const float4*)(A + (size_t)(m0 + r) * K + k0 + c4 * 4);
        As[c4 * 4 + 0][r] = av.x; As[c4 * 4 + 1][r] = av.y;
        As[c4 * 4 + 2][r] = av.z; As[c4 * 4 + 3][r] = av.w;
        if (BKN == 0) {
            float4 bv = *(const float4*)(B + (size_t)(n0 + r) * K + k0 + c4 * 4);
            Bs[c4 * 4 + 0][r] = bv.x; Bs[c4 * 4 + 1][r] = bv.y;
            Bs[c4 * 4 + 2][r] = bv.z; Bs[c4 * 4 + 3][r] = bv.w;
        } else {
            float4 bv = *(const float4*)(B + (size_t)(k0 + (tid >> 4)) * N + n0 + (tid & 15) * 4);
            Bs[tid >> 4][(tid & 15) * 4 + 0] = bv.x; Bs[tid >> 4][(tid & 15) * 4 + 1] = bv.y;
            Bs[tid >> 4][(tid & 15) * 4 + 2] = bv.z; Bs[tid >> 4][(tid & 15) * 4 + 3] = bv.w;
        }
        __syncthreads();
#pragma unroll
        for (int kk = 0; kk < 16; kk++) {
            float a_[4];
#pragma unroll
            for (int i = 0; i < 4; i++) a_[i] = As[kk][ty * 4 + i];
            float4 bb = *(const float4*)&Bs[kk][tx * 4];
#pragma unroll
            for (int i = 0; i < 4; i++) {
                acc[i][0] = fmaf(a_[i], bb.x, acc[i][0]);
                acc[i][1] = fmaf(a_[i], bb.y, acc[i][1]);
                acc[i][2] = fmaf(a_[i], bb.z, acc[i][2]);
                acc[i][3] = fmaf(a_[i], bb.w, acc[i][3]);
            }
        }
        __syncthreads();
    }
#pragma unroll
    for (int i = 0; i < 4; i++) {
        float4 v = make_float4(acc[i][0], acc[i][1], acc[i][2], acc[i][3]);
        if (RELU) {
            v.x = fmaxf(v.x, 0.f); v.y = fmaxf(v.y, 0.f);
            v.z = fmaxf(v.z, 0.f); v.w = fmaxf(v.w, 0.f);
        }
        *(float4*)(C + (size_t)(m0 + ty * 4 + i) * N + n0 + tx * 4) = v;
    }
}

// ---------------------------------------------------------------- iv_norm = l2norm(ind_vec) per row
__global__ void k_rownorm(const float* __restrict__ iv, float* __restrict__ ivn) {
    int b = blockIdx.x, lane = threadIdx.x;
    float v[8]; float s = 0.f;
#pragma unroll
    for (int k = 0; k < 8; k++) {
        v[k] = iv[(size_t)b * C_ + lane + 64 * k];
        s = fmaf(v[k], v[k], s);
    }
#pragma unroll
    for (int off = 32; off > 0; off >>= 1) s += __shfl_xor(s, off, 64);
    float rn = 1.0f / fmaxf(sqrtf(s), 1e-12f);
#pragma unroll
    for (int k = 0; k < 8; k++) ivn[(size_t)b * C_ + lane + 64 * k] = v[k] * rn;
}

// ---------------------------------------------------------------- Abf = bf16([Wv; U; 0pad]) [768][512]
__global__ void k_prepA(const float* __restrict__ Wv, const float* __restrict__ U,
                        unsigned short* __restrict__ Abf) {
    int r = blockIdx.x, tid = threadIdx.x;
    for (int i = 0; i < 2; i++) {
        int c = tid + i * 256;
        float v = 0.f;
        if (r < 512) v = Wv[(size_t)r * C_ + c];
        else if (r < 704) v = U[(size_t)(r - 512) * C_ + c];
        Abf[(size_t)r * C_ + c] = f2bf(v);
    }
}

// ---------------------------------------------------------------- ev[b][c][p] fp32 -> evT[bl][p][c] bf16
__global__ void k_transpose(const float* __restrict__ ev, unsigned short* __restrict__ evT,
                            float* __restrict__ evsum, int doevm, int b0) {
    __shared__ float t32[32][33];
    int bl = blockIdx.z, b = b0 + bl;
    int c0 = blockIdx.y * 32, p0 = blockIdx.x * 32;
    int t = threadIdx.x;
    int lr = t >> 3, lc = t & 7;
    float4 v = make_float4(0.f, 0.f, 0.f, 0.f);
    int p = p0 + lc * 4;
    const float* src = ev + ((size_t)b * C_ + c0 + lr) * HW_;
    if (p + 3 < HW_) v = *(const float4*)(src + p);
    else { for (int j = 0; j < 4; j++) if (p + j < HW_) ((float*)&v)[j] = src[p + j]; }
    if (doevm) {
        float rs = v.x + v.y + v.z + v.w;
        rs += __shfl_xor(rs, 1, 8);
        rs += __shfl_xor(rs, 2, 8);
        rs += __shfl_xor(rs, 4, 8);
        if (lc == 0) atomicAdd(&evsum[b * C_ + c0 + lr], rs * (1.0f / HW_));
    }
    t32[lr][lc * 4 + 0] = v.x; t32[lr][lc * 4 + 1] = v.y;
    t32[lr][lc * 4 + 2] = v.z; t32[lr][lc * 4 + 3] = v.w;
    __syncthreads();
    ushort4 o;
    o.x = f2bf(t32[lc * 4 + 0][lr]);
    o.y = f2bf(t32[lc * 4 + 1][lr]);
    o.z = f2bf(t32[lc * 4 + 2][lr]);
    o.w = f2bf(t32[lc * 4 + 3][lr]);
    *(ushort4*)(evT + ((size_t)bl * PPAD + p0 + lr) * C_ + c0 + lc * 4) = o;
}

// ---------------------------------------------------------------- MFMA GEMM: [Wv;U](704x512) @ ev[b](512x784)
// tiles 128x128, BK=32, 4 waves 2x2, wave 64x64 = 4x4 frags of 16x16x32
__global__ __launch_bounds__(256, 4)
void k_gemm(const unsigned short* __restrict__ Abf, const unsigned short* __restrict__ evT,
            float* __restrict__ n2, unsigned short* __restrict__ Tb, int b0, int nb) {
    __shared__ unsigned short As[2][4096];   // [128][32]
    __shared__ unsigned short Bs[2][4096];   // [128][32]

    int id = blockIdx.x;
    int xcd = id & 7, slot = id >> 3;
    int S = (nb * 42 + 7) >> 3;
    int w = xcd * S + slot;
    if (w >= nb * 42) return;
    int bl = w / 42, rem = w % 42;
    int pt = rem / 6, ot = rem % 6;
    int o0 = ot * 128, p0 = pt * 128;

    int tid = threadIdx.x;
    int wid = tid >> 6, lane = tid & 63;
    int wy = wid >> 1, wx = wid & 1;
    int l15 = lane & 15, l4 = lane >> 4;

    const unsigned short* Ag = Abf + ((size_t)o0 + (tid >> 2)) * C_ + (tid & 3) * 8;
    const unsigned short* Bg = evT + ((size_t)bl * PPAD + p0 + (tid >> 2)) * C_ + (tid & 3) * 8;
    int lds_off = wid * 512 + lane * 8;      // ushort elements; = linear tid*16 bytes

    f4 acc[4][4] = {};
    int cur = 0;

#define STAGE(buf, k0) do { \
    gld16(Ag + (k0),             &As[buf][0] + lds_off); \
    gld16(Ag + (k0) + 64 * C_,   &As[buf][2048] + lds_off); \
    gld16(Bg + (k0),             &Bs[buf][0] + lds_off); \
    gld16(Bg + (k0) + 64 * C_,   &Bs[buf][2048] + lds_off); \
} while (0)

    STAGE(0, 0);
    __syncthreads();
    for (int t = 0; t < 16; ++t) {
        if (t < 15) STAGE(cur ^ 1, (t + 1) * 32);
        const s8bf* Ar = (const s8bf*)&As[cur][0];
        const s8bf* Br = (const s8bf*)&Bs[cur][0];
        s8bf a[4], b[4];
#pragma unroll
        for (int mi = 0; mi < 4; mi++) a[mi] = Ar[(wy * 64 + mi * 16 + l15) * 4 + l4];
#pragma unroll
        for (int ni = 0; ni < 4; ni++) b[ni] = Br[(wx * 64 + ni * 16 + l15) * 4 + l4];
#pragma unroll
        for (int mi = 0; mi < 4; mi++)
#pragma unroll
            for (int ni = 0; ni < 4; ni++)
                acc[mi][ni] = __builtin_amdgcn_mfma_f32_16x16x32_bf16(a[mi], b[ni], acc[mi][ni], 0, 0, 0);
        __syncthreads();
        cur ^= 1;
    }
#undef STAGE

    if (ot < 4) {
        // norm tiles: n2[b,p] += sum_o acc^2  (reduce buffer aliases dead As)
        float* red = (float*)&As[0][0];
#pragma unroll
        for (int ni = 0; ni < 4; ni++) {
            float s = 0.f;
#pragma unroll
            for (int mi = 0; mi < 4; mi++)
#pragma unroll
                for (int r = 0; r < 4; r++) { float x = acc[mi][ni][r]; s = fmaf(x, x, s); }
            red[(wy * 4 + l4) * 128 + wx * 64 + ni * 16 + l15] = s;
        }
        __syncthreads();
        if (tid < 128) {
            float s = 0.f;
#pragma unroll
            for (int q = 0; q < 8; q++) s += red[q * 128 + tid];
            int p = p0 + tid;
            if (p < HW_) atomicAdd(&n2[(size_t)(b0 + bl) * HW_ + p], s);
        }
    } else {
        int dbase = o0 - 512 + wy * 64;
#pragma unroll
        for (int mi = 0; mi < 4; mi++)
#pragma unroll
            for (int r = 0; r < 4; r++) {
                int dd = dbase + mi * 16 + l4 * 4 + r;
                if (dd < B_) {
                    size_t rowoff = ((size_t)bl * B_ + dd) * HW_;
#pragma unroll
                    for (int ni = 0; ni < 4; ni++) {
                        int p = p0 + wx * 64 + ni * 16 + l15;
                        if (p < HW_) Tb[rowoff + p] = f2bf(acc[mi][ni][r]);
                    }
                }
            }
    }
}

// ---------------------------------------------------------------- invn[b,p] = 1/max(sqrt(n2),1e-12)
__global__ void k_invn(const float* __restrict__ n2, float* __restrict__ invn, int b0, int n) {
    int i = blockIdx.x * 256 + threadIdx.x;
    if (i >= n) return;
    size_t idx = (size_t)b0 * HW_ + i;
    invn[idx] = 1.0f / fmaxf(sqrtf(n2[idx]), 1e-12f);
}

// ---------------------------------------------------------------- pool: wave per (b,d); bisection top-k
__global__ __launch_bounds__(256)
void k_pool(const unsigned short* __restrict__ T, const float* __restrict__ invn,
            float* __restrict__ SP, float* __restrict__ SN, int b0) {
    int tid = threadIdx.x;
    int wv = tid >> 6, lane = tid & 63;
    int d = blockIdx.x * 4 + wv;
    int bl = blockIdx.y, b = b0 + bl;
    const unsigned short* Trow = T + ((size_t)bl * B_ + d) * HW_;
    const float* nrow = invn + (size_t)b * HW_;
    float sv[13];
#pragma unroll
    for (int i = 0; i < 12; i++) {
        int p = lane + i * 64;
        sv[i] = bf2f(Trow[p]) * nrow[p];
    }
    {
        int p = lane + 768;
        sv[12] = (p < HW_) ? bf2f(Trow[p]) * nrow[p] : __uint_as_float(0x7FC00000u); // NaN pad
    }
    float lo = -1.1f, hi = 1.1f;
    for (int it = 0; it < 22; ++it) {
        float mid = 0.5f * (lo + hi);
        int c = 0;
#pragma unroll
        for (int i = 0; i < 13; i++) c += __popcll(__ballot(sv[i] >= mid));
        if (c >= TPK) lo = mid; else hi = mid;
    }
    float thrp = lo;
    lo = -1.1f; hi = 1.1f;
    for (int it = 0; it < 22; ++it) {
        float mid = 0.5f * (lo + hi);
        int c = 0;
#pragma unroll
        for (int i = 0; i < 13; i++) c += __popcll(__ballot(sv[i] <= mid));
        if (c >= TPK) hi = mid; else lo = mid;
    }
    float thrn = hi;
    const float its = 1.0f / 0.03f;
    float spn = 0.f, spd = 0.f, snn = 0.f, snd = 0.f;
#pragma unroll
    for (int i = 0; i < 13; i++) {
        if (i == 12 && lane >= 16) continue;
        float s = sv[i];
        float mp = sigf((s - thrp) * its);
        float mn = sigf(-(s - thrn) * its);
        spn += s * mp; spd += mp;
        snn += s * mn; snd += mn;
    }
    for (int off = 32; off > 0; off >>= 1) {
        spn += __shfl_down(spn, off, 64);
        spd += __shfl_down(spd, off, 64);
        snn += __shfl_down(snn, off, 64);
        snd += __shfl_down(snd, off, 64);
    }
    if (lane == 0) {
        SP[b * B_ + d] = spn / spd;
        SN[b * B_ + d] = snn / snd;
    }
}

// ---------------------------------------------------------------- CE losses
__global__ void k_loss12(const float* __restrict__ SP, const float* __restrict__ SN,
                         float* __restrict__ acc) {
    __shared__ float red[128];
    int i = blockIdx.x, tid = threadIdx.x;
    const float itc = 1.0f / 0.07f;
    for (int phase = 0; phase < 2; phase++) {
        float mx = -INFINITY;
        for (int j = tid; j < 2 * B_; j += 128) {
            float v;
            if (phase == 0) v = (j < B_ ? SP[i * B_ + j] : SN[i * B_ + (j - B_)]);
            else            v = (j < B_ ? SP[j * B_ + i] : SN[(j - B_) * B_ + i]);
            mx = fmaxf(mx, v * itc);
        }
        red[tid] = mx; __syncthreads();
        for (int s = 64; s > 0; s >>= 1) { if (tid < s) red[tid] = fmaxf(red[tid], red[tid + s]); __syncthreads(); }
        mx = red[0]; __syncthreads();
        float se = 0.f;
        for (int j = tid; j < 2 * B_; j += 128) {
            float v;
            if (phase == 0) v = (j < B_ ? SP[i * B_ + j] : SN[i * B_ + (j - B_)]);
            else            v = (j < B_ ? SP[j * B_ + i] : SN[(j - B_) * B_ + i]);
            se += __expf(v * itc - mx);
        }
        red[tid] = se; __syncthreads();
        for (int s = 64; s > 0; s >>= 1) { if (tid < s) red[tid] += red[tid + s]; __syncthreads(); }
        if (tid == 0) {
            float lse = logf(red[0]) + mx;
            atomicAdd(&acc[phase], lse - SP[i * B_ + i] * itc);
        }
        __syncthreads();
    }
}

// ---------------------------------------------------------------- fused distance matrix
// D[i][j] = (i==j) ? raw : raw*vv/191,  raw = sum_c (iv[i,c]-fa[j,c]+1e-6)^2, vv = ivn[i].ivn[j]
__global__ __launch_bounds__(256)
void k_distmat(const float* __restrict__ iv, const float* __restrict__ ivn,
               const float* __restrict__ fa, float* __restrict__ D) {
    __shared__ float Ai[16][68], An[16][68], Bf[16][68], Bn[16][68];
    int i0 = blockIdx.y * 64, j0 = blockIdx.x * 64;
    int tid = threadIdx.x;
    int tx = tid & 15, ty = tid >> 4;
    int r = tid >> 2, c4 = tid & 3;
    float accD[4][4], accV[4][4];
#pragma unroll
    for (int i = 0; i < 4; i++)
#pragma unroll
        for (int j = 0; j < 4; j++) { accD[i][j] = 0.f; accV[i][j] = 0.f; }

    for (int k0 = 0; k0 < C_; k0 += 16) {
        float4 v;
        v = *(const float4*)(iv + (size_t)(i0 + r) * C_ + k0 + c4 * 4);
        Ai[c4*4+0][r]=v.x; Ai[c4*4+1][r]=v.y; Ai[c4*4+2][r]=v.z; Ai[c4*4+3][r]=v.w;
        v = *(const float4*)(ivn + (size_t)(i0 + r) * C_ + k0 + c4 * 4);
        An[c4*4+0][r]=v.x; An[c4*4+1][r]=v.y; An[c4*4+2][r]=v.z; An[c4*4+3][r]=v.w;
        v = *(const float4*)(fa + (size_t)(j0 + r) * C_ + k0 + c4 * 4);
        Bf[c4*4+0][r]=v.x; Bf[c4*4+1][r]=v.y; Bf[c4*4+2][r]=v.z; Bf[c4*4+3][r]=v.w;
        v = *(const float4*)(ivn + (size_t)(j0 + r) * C_ + k0 + c4 * 4);
        Bn[c4*4+0][r]=v.x; Bn[c4*4+1][r]=v.y; Bn[c4*4+2][r]=v.z; Bn[c4*4+3][r]=v.w;
        __syncthreads();
#pragma unroll
        for (int kk = 0; kk < 16; kk++) {
            float ai[4], an[4];
#pragma unroll
            for (int i = 0; i < 4; i++) { ai[i] = Ai[kk][ty*4+i]; an[i] = An[kk][ty*4+i]; }
            float4 bf = *(const float4*)&Bf[kk][tx*4];
            float4 bn = *(const float4*)&Bn[kk][tx*4];
#pragma unroll
            for (int i = 0; i < 4; i++) {
                float d0 = ai[i] - bf.x + 1e-6f; accD[i][0] = fmaf(d0, d0, accD[i][0]);
                float d1 = ai[i] - bf.y + 1e-6f; accD[i][1] = fmaf(d1, d1, accD[i][1]);
                float d2 = ai[i] - bf.z + 1e-6f; accD[i][2] = fmaf(d2, d2, accD[i][2]);
                float d3 = ai[i] - bf.w + 1e-6f; accD[i][3] = fmaf(d3, d3, accD[i][3]);
                accV[i][0] = fmaf(an[i], bn.x, accV[i][0]);
                accV[i][1] = fmaf(an[i], bn.y, accV[i][1]);
                accV[i][2] = fmaf(an[i], bn.z, accV[i][2]);
                accV[i][3] = fmaf(an[i], bn.w, accV[i][3]);
            }
        }
        __syncthreads();
    }
#pragma unroll
    for (int i = 0; i < 4; i++)
#pragma unroll
        for (int j = 0; j < 4; j++) {
            int gi = i0 + ty * 4 + i, gj = j0 + tx * 4 + j;
            float val = (gi == gj) ? accD[i][j] : accD[i][j] * accV[i][j] * (1.0f / 191.0f);
            D[gi * B_ + gj] = val;
        }
}

// ---------------------------------------------------------------- final scalar assembly
__global__ void k_final2(const float* __restrict__ acc, const float* __restrict__ D,
                         float* __restrict__ out) {
    __shared__ float red[256];
    int tid = threadIdx.x;
    float v3 = 0.f, v4 = 0.f;
    if (tid < B_) {
        float rs = 0.f, cs = 0.f;
        for (int j = 0; j < B_; j++) rs += D[tid * B_ + j];
        for (int i = 0; i < B_; i++) cs += D[i * B_ + tid];
        v3 = fmaxf(rs + 0.6f, 0.f);
        v4 = fmaxf(cs + 0.6f, 0.f);
    }
    red[tid] = v3; __syncthreads();
    for (int s = 128; s > 0; s >>= 1) { if (tid < s) red[tid] += red[tid + s]; __syncthreads(); }
    float l3 = red[0] / B_;
    __syncthreads();
    red[tid] = v4; __syncthreads();
    for (int s = 128; s > 0; s >>= 1) { if (tid < s) red[tid] += red[tid + s]; __syncthreads(); }
    float l4 = red[0] / B_;
    if (tid == 0) {
        out[0] = 0.5f * (acc[0] + acc[1]) / B_;
        out[1] = 0.5f * (l3 + l4);
    }
}

extern "C" void kernel_launch(void* const* d_in, const int* in_sizes, int n_in,
                              void* d_out, int out_size, void* d_ws, size_t ws_size,
                              hipStream_t stream) {
    const float* ev  = (const float*)d_in[0];
    const float* ea  = (const float*)d_in[1];
    const float* Wv  = (const float*)d_in[2];
    const float* Wa1 = (const float*)d_in[3];
    const float* Wa2 = (const float*)d_in[4];
    float* out = (float*)d_out;
    float* ws  = (float*)d_ws;

    size_t off = 0;
    float* evmean  = ws + off; off += B_ * C_;
    float* ind_vec = ws + off; off += B_ * C_;
    float* iv_norm = ws + off; off += B_ * C_;
    float* Ub      = ws + off; off += B_ * C_;
    float* fa      = ws + off; off += B_ * C_;
    float* Hb      = ws + off; off += B_ * C_;
    float* n2      = ws + off; off += B_ * HW_;
    float* invn    = ws + off; off += B_ * HW_;
    float* SPb     = ws + off; off += B_ * B_;
    float* SNb     = ws + off; off += B_ * B_;
    float* Db      = ws + off; off += B_ * B_;
    float* accb    = ws + off; off += 16;
    unsigned short* Abf = (unsigned short*)(ws + off); off += 768 * C_ / 2;

    // per-b chunk buffers: evT (PPAD*C_ bf16) + Tb (B_*HW_ bf16)
    size_t perB_f = (size_t)PPAD * C_ / 2 + (size_t)B_ * HW_ / 2;
    size_t avail  = ws_size / 4 > off ? ws_size / 4 - off : 0;
    int chunk = (int)(avail / perB_f);
    if (chunk > B_) chunk = B_;
    if (chunk < 1) chunk = 1;
    unsigned short* evT = (unsigned short*)(ws + off);
    unsigned short* Tb  = evT + (size_t)chunk * PPAD * C_;

    hipMemsetAsync(n2,   0, B_ * HW_ * sizeof(float), stream);
    hipMemsetAsync(accb, 0, 2 * sizeof(float), stream);

    dim3 g24(C_ / 64, B_ / 64);   // N=512, M=192

    if (chunk >= B_) {
        // single transpose pass also computes evmean (atomics)
        hipMemsetAsync(evmean, 0, B_ * C_ * sizeof(float), stream);
        dim3 gt(PPAD / 32, C_ / 32, B_);
        k_transpose<<<gt, 256, 0, stream>>>(ev, evT, evmean, 1, 0);
    } else {
        k_evmean<<<B_ * C_ / 4, 256, 0, stream>>>(ev, evmean);
    }

    // visual projection chain (tiled fp32 GEMMs)
    k32<0, 0><<<g24, 256, 0, stream>>>(evmean, Wv, ind_vec, B_, C_, C_);
    k_rownorm<<<B_, 64, 0, stream>>>(ind_vec, iv_norm);
    k32<1, 0><<<g24, 256, 0, stream>>>(iv_norm, Wv, Ub, B_, C_, C_);
    k_prepA<<<768, 256, 0, stream>>>(Wv, Ub, Abf);

    // audio chain
    k32<0, 1><<<g24, 256, 0, stream>>>(ea, Wa1, Hb, B_, C_, 2048);
    k32<0, 0><<<g24, 256, 0, stream>>>(Hb, Wa2, fa, B_, C_, C_);

    if (chunk >= B_) {
        int grid = 8 * ((B_ * 42 + 7) / 8);
        k_gemm<<<grid, 256, 0, stream>>>(Abf, evT, n2, Tb, 0, B_);
        int n = B_ * HW_;
        k_invn<<<(n + 255) / 256, 256, 0, stream>>>(n2, invn, 0, n);
        dim3 gp(B_ / 4, B_);
        k_pool<<<gp, 256, 0, stream>>>(Tb, invn, SPb, SNb, 0);
    } else {
        for (int b0 = 0; b0 < B_; b0 += chunk) {
            int nb = (B_ - b0 < chunk) ? (B_ - b0) : chunk;
            dim3 gt(PPAD / 32, C_ / 32, nb);
            k_transpose<<<gt, 256, 0, stream>>>(ev, evT, evmean, 0, b0);
            int grid = 8 * ((nb * 42 + 7) / 8);
            k_gemm<<<grid, 256, 0, stream>>>(Abf, evT, n2, Tb, b0, nb);
            int n = nb * HW_;
            k_invn<<<(n + 255) / 256, 256, 0, stream>>>(n2, invn, b0, n);
            dim3 gp(B_ / 4, nb);
            k_pool<<<gp, 256, 0, stream>>>(Tb, invn, SPb, SNb, b0);
        }
    }

    k_loss12<<<B_, 128, 0, stream>>>(SPb, SNb, accb);
    dim3 gd(B_ / 64, B_ / 64);
    k_distmat<<<gd, 256, 0, stream>>>(ind_vec, iv_norm, fa, Db);
    k_final2<<<1, 256, 0, stream>>>(accb, Db, out);
}

// Round 5
// 689.860 us; speedup vs baseline: 3.6901x; 1.0005x over previous
//
#include <hip/hip_runtime.h>
#include <math.h>

#define B_   192
#define C_   512
#define HW_  784
#define TPK  23          // int(784*0.03)
#define PPAD 896         // 7 p-tiles of 128

typedef __attribute__((ext_vector_type(8))) short s8bf;
typedef __attribute__((ext_vector_type(4))) float f4;
typedef __attribute__((ext_vector_type(8))) unsigned short us8;

__device__ __forceinline__ float sigf(float x) {
    return 1.0f / (1.0f + __expf(-x));
}
__device__ __forceinline__ unsigned short f2bf(float f) {
    unsigned u = __float_as_uint(f);
    unsigned r = u + 0x7FFFu + ((u >> 16) & 1u);
    return (unsigned short)(r >> 16);
}
__device__ __forceinline__ float bf2f(unsigned short u) {
    return __uint_as_float(((unsigned)u) << 16);
}
__device__ __forceinline__ void gld16(const unsigned short* g, unsigned short* l) {
    __builtin_amdgcn_global_load_lds((const __attribute__((address_space(1))) unsigned int*)g,
                                     (__attribute__((address_space(3))) unsigned int*)l, 16, 0, 0);
}

// ---------------------------------------------------------------- evmean (fallback only)
__global__ void k_evmean(const float* __restrict__ ev, float* __restrict__ evmean) {
    int row  = blockIdx.x * 4 + (threadIdx.x >> 6);
    int lane = threadIdx.x & 63;
    const float4* s4 = (const float4*)(ev + (size_t)row * HW_);
    float s = 0.f;
    for (int i = lane; i < HW_ / 4; i += 64) {
        float4 v = s4[i];
        s += v.x + v.y + v.z + v.w;
    }
    for (int off = 32; off > 0; off >>= 1) s += __shfl_down(s, off, 64);
    if (lane == 0) evmean[row] = s * (1.0f / HW_);
}

// ---------------------------------------------------------------- tiled fp32 GEMM
// BKN=0: B[N][K] (B^T), BKN=1: B[K][N].  BF16OUT: write bf16 (ushort) instead of fp32.
template<int BKN, int RELU, int BF16OUT>
__global__ __launch_bounds__(256)
void k32(const float* __restrict__ A, const float* __restrict__ B,
         void* __restrict__ Cv, int M, int N, int K) {
    __shared__ float As[16][68];
    __shared__ float Bs[16][68];
    int m0 = blockIdx.y * 64, n0 = blockIdx.x * 64;
    int tid = threadIdx.x;
    int tx = tid & 15, ty = tid >> 4;
    int r = tid >> 2, c4 = tid & 3;

    float acc[4][4];
#pragma unroll
    for (int i = 0; i < 4; i++)
#pragma unroll
        for (int j = 0; j < 4; j++) acc[i][j] = 0.f;

    for (int k0 = 0; k0 < K; k0 += 16) {
        float4 av = *(const float4*)(A + (size_t)(m0 + r) * K + k0 + c4 * 4);
        As[c4 * 4 + 0][r] = av.x; As[c4 * 4 + 1][r] = av.y;
        As[c4 * 4 + 2][r] = av.z; As[c4 * 4 + 3][r] = av.w;
        if (BKN == 0) {
            float4 bv = *(const float4*)(B + (size_t)(n0 + r) * K + k0 + c4 * 4);
            Bs[c4 * 4 + 0][r] = bv.x; Bs[c4 * 4 + 1][r] = bv.y;
            Bs[c4 * 4 + 2][r] = bv.z; Bs[c4 * 4 + 3][r] = bv.w;
        } else {
            float4 bv = *(const float4*)(B + (size_t)(k0 + (tid >> 4)) * N + n0 + (tid & 15) * 4);
            Bs[tid >> 4][(tid & 15) * 4 + 0] = bv.x; Bs[tid >> 4][(tid & 15) * 4 + 1] = bv.y;
            Bs[tid >> 4][(tid & 15) * 4 + 2] = bv.z; Bs[tid >> 4][(tid & 15) * 4 + 3] = bv.w;
        }
        __syncthreads();
#pragma unroll
        for (int kk = 0; kk < 16; kk++) {
            float a_[4];
#pragma unroll
            for (int i = 0; i < 4; i++) a_[i] = As[kk][ty * 4 + i];
            float4 bb = *(const float4*)&Bs[kk][tx * 4];
#pragma unroll
            for (int i = 0; i < 4; i++) {
                acc[i][0] = fmaf(a_[i], bb.x, acc[i][0]);
                acc[i][1] = fmaf(a_[i], bb.y, acc[i][1]);
                acc[i][2] = fmaf(a_[i], bb.z, acc[i][2]);
                acc[i][3] = fmaf(a_[i], bb.w, acc[i][3]);
            }
        }
        __syncthreads();
    }
#pragma unroll
    for (int i = 0; i < 4; i++) {
        float4 v = make_float4(acc[i][0], acc[i][1], acc[i][2], acc[i][3]);
        if (RELU) {
            v.x = fmaxf(v.x, 0.f); v.y = fmaxf(v.y, 0.f);
            v.z = fmaxf(v.z, 0.f); v.w = fmaxf(v.w, 0.f);
        }
        if (BF16OUT) {
            unsigned short* C16 = (unsigned short*)Cv;
            ushort4 o;
            o.x = f2bf(v.x); o.y = f2bf(v.y); o.z = f2bf(v.z); o.w = f2bf(v.w);
            *(ushort4*)(C16 + (size_t)(m0 + ty * 4 + i) * N + n0 + tx * 4) = o;
        } else {
            float* C = (float*)Cv;
            *(float4*)(C + (size_t)(m0 + ty * 4 + i) * N + n0 + tx * 4) = v;
        }
    }
}

// ---------------------------------------------------------------- iv_norm = l2norm(ind_vec) per row
__global__ void k_rownorm(const float* __restrict__ iv, float* __restrict__ ivn) {
    int b = blockIdx.x, lane = threadIdx.x;
    float v[8]; float s = 0.f;
#pragma unroll
    for (int k = 0; k < 8; k++) {
        v[k] = iv[(size_t)b * C_ + lane + 64 * k];
        s = fmaf(v[k], v[k], s);
    }
#pragma unroll
    for (int off = 32; off > 0; off >>= 1) s += __shfl_xor(s, off, 64);
    float rn = 1.0f / fmaxf(sqrtf(s), 1e-12f);
#pragma unroll
    for (int k = 0; k < 8; k++) ivn[(size_t)b * C_ + lane + 64 * k] = v[k] * rn;
}

// ---------------------------------------------------------------- Abf rows 0..511 = bf16(Wv), rows 704..767 = 0
__global__ void k_prepA(const float* __restrict__ Wv, unsigned short* __restrict__ Abf) {
    int r = blockIdx.x, tid = threadIdx.x;
    int row = (r < 512) ? r : (192 + r);   // 512..575 -> 704..767 zero pad
    for (int i = 0; i < 2; i++) {
        int c = tid + i * 256;
        float v = (r < 512) ? Wv[(size_t)r * C_ + c] : 0.f;
        Abf[(size_t)row * C_ + c] = f2bf(v);
    }
}

// ---------------------------------------------------------------- ev[b][c][p] fp32 -> evT[bl][p][c] bf16 (64x64 tiles)
__global__ __launch_bounds__(256)
void k_transpose64(const float* __restrict__ ev, unsigned short* __restrict__ evT,
                   float* __restrict__ evsum, int doevm, int b0) {
    __shared__ float t[64][65];
    int bl = blockIdx.z, b = b0 + bl;
    int c0 = blockIdx.y * 64, p0 = blockIdx.x * 64;
    int tid = threadIdx.x;
    int cl = tid >> 4;            // 0..15 c-row within pass
    int pc = tid & 15;            // p-chunk of 4
    int p = p0 + pc * 4;
#pragma unroll
    for (int q = 0; q < 4; q++) {
        int c_local = q * 16 + cl;
        const float* src = ev + ((size_t)b * C_ + c0 + c_local) * HW_;
        float4 v = make_float4(0.f, 0.f, 0.f, 0.f);
        if (p + 3 < HW_) v = *(const float4*)(src + p);
        else if (p < HW_) { for (int j = 0; j < 4; j++) if (p + j < HW_) ((float*)&v)[j] = src[p + j]; }
        if (doevm) {
            float rs = v.x + v.y + v.z + v.w;
            rs += __shfl_xor(rs, 1, 16);
            rs += __shfl_xor(rs, 2, 16);
            rs += __shfl_xor(rs, 4, 16);
            rs += __shfl_xor(rs, 8, 16);
            if (pc == 0) atomicAdd(&evsum[b * C_ + c0 + c_local], rs * (1.0f / HW_));
        }
        t[c_local][pc * 4 + 0] = v.x; t[c_local][pc * 4 + 1] = v.y;
        t[c_local][pc * 4 + 2] = v.z; t[c_local][pc * 4 + 3] = v.w;
    }
    __syncthreads();
    int r = tid >> 3;   // 0..31 p-row
    int j = tid & 7;    // c-chunk of 8
#pragma unroll
    for (int q = 0; q < 2; q++) {
        int row = r + q * 32;
        us8 o;
#pragma unroll
        for (int k = 0; k < 8; k++) o[k] = f2bf(t[j * 8 + k][row]);
        *(us8*)(evT + ((size_t)bl * PPAD + p0 + row) * C_ + c0 + j * 8) = o;
    }
}

// ---------------------------------------------------------------- MFMA GEMM: [Wv;U](704x512) @ ev[b](512x784)
__global__ __launch_bounds__(256, 4)
void k_gemm(const unsigned short* __restrict__ Abf, const unsigned short* __restrict__ evT,
            float* __restrict__ n2, unsigned short* __restrict__ Tb, int b0, int nb) {
    __shared__ unsigned short As[2][4096];   // [128][32]
    __shared__ unsigned short Bs[2][4096];   // [128][32]

    int id = blockIdx.x;
    int xcd = id & 7, slot = id >> 3;
    int S = (nb * 42 + 7) >> 3;
    int w = xcd * S + slot;
    if (w >= nb * 42) return;
    int bl = w / 42, rem = w % 42;
    int pt = rem / 6, ot = rem % 6;
    int o0 = ot * 128, p0 = pt * 128;

    int tid = threadIdx.x;
    int wid = tid >> 6, lane = tid & 63;
    int wy = wid >> 1, wx = wid & 1;
    int l15 = lane & 15, l4 = lane >> 4;

    const unsigned short* Ag = Abf + ((size_t)o0 + (tid >> 2)) * C_ + (tid & 3) * 8;
    const unsigned short* Bg = evT + ((size_t)bl * PPAD + p0 + (tid >> 2)) * C_ + (tid & 3) * 8;
    int lds_off = wid * 512 + lane * 8;

    f4 acc[4][4] = {};
    int cur = 0;

#define STAGE(buf, k0) do { \
    gld16(Ag + (k0),             &As[buf][0] + lds_off); \
    gld16(Ag + (k0) + 64 * C_,   &As[buf][2048] + lds_off); \
    gld16(Bg + (k0),             &Bs[buf][0] + lds_off); \
    gld16(Bg + (k0) + 64 * C_,   &Bs[buf][2048] + lds_off); \
} while (0)

    STAGE(0, 0);
    __syncthreads();
    for (int t = 0; t < 16; ++t) {
        if (t < 15) STAGE(cur ^ 1, (t + 1) * 32);
        const s8bf* Ar = (const s8bf*)&As[cur][0];
        const s8bf* Br = (const s8bf*)&Bs[cur][0];
        s8bf a[4], b[4];
#pragma unroll
        for (int mi = 0; mi < 4; mi++) a[mi] = Ar[(wy * 64 + mi * 16 + l15) * 4 + l4];
#pragma unroll
        for (int ni = 0; ni < 4; ni++) b[ni] = Br[(wx * 64 + ni * 16 + l15) * 4 + l4];
#pragma unroll
        for (int mi = 0; mi < 4; mi++)
#pragma unroll
            for (int ni = 0; ni < 4; ni++)
                acc[mi][ni] = __builtin_amdgcn_mfma_f32_16x16x32_bf16(a[mi], b[ni], acc[mi][ni], 0, 0, 0);
        __syncthreads();
        cur ^= 1;
    }
#undef STAGE

    if (ot < 4) {
        float* red = (float*)&As[0][0];
#pragma unroll
        for (int ni = 0; ni < 4; ni++) {
            float s = 0.f;
#pragma unroll
            for (int mi = 0; mi < 4; mi++)
#pragma unroll
                for (int r = 0; r < 4; r++) { float x = acc[mi][ni][r]; s = fmaf(x, x, s); }
            red[(wy * 4 + l4) * 128 + wx * 64 + ni * 16 + l15] = s;
        }
        __syncthreads();
        if (tid < 128) {
            float s = 0.f;
#pragma unroll
            for (int q = 0; q < 8; q++) s += red[q * 128 + tid];
            int p = p0 + tid;
            if (p < HW_) atomicAdd(&n2[(size_t)(b0 + bl) * HW_ + p], s);
        }
    } else {
        int dbase = o0 - 512 + wy * 64;
#pragma unroll
        for (int mi = 0; mi < 4; mi++)
#pragma unroll
            for (int r = 0; r < 4; r++) {
                int dd = dbase + mi * 16 + l4 * 4 + r;
                if (dd < B_) {
                    size_t rowoff = ((size_t)bl * B_ + dd) * HW_;
#pragma unroll
                    for (int ni = 0; ni < 4; ni++) {
                        int p = p0 + wx * 64 + ni * 16 + l15;
                        if (p < HW_) Tb[rowoff + p] = f2bf(acc[mi][ni][r]);
                    }
                }
            }
    }
}

// ---------------------------------------------------------------- pool: wave per (b,d); dual interleaved bisection
__global__ __launch_bounds__(256)
void k_pool(const unsigned short* __restrict__ T, const float* __restrict__ n2,
            float* __restrict__ SP, float* __restrict__ SN, int b0) {
    int tid = threadIdx.x;
    int wv = tid >> 6, lane = tid & 63;
    int d = blockIdx.x * 4 + wv;
    int bl = blockIdx.y, b = b0 + bl;
    const unsigned short* Trow = T + ((size_t)bl * B_ + d) * HW_;
    const float* nrow = n2 + (size_t)b * HW_;
    float sv[13];
#pragma unroll
    for (int i = 0; i < 12; i++) {
        int p = lane + i * 64;
        float nv = fmaxf(sqrtf(nrow[p]), 1e-12f);
        sv[i] = bf2f(Trow[p]) / nv;
    }
    {
        int p = lane + 768;
        if (p < HW_) {
            float nv = fmaxf(sqrtf(nrow[p]), 1e-12f);
            sv[12] = bf2f(Trow[p]) / nv;
        } else sv[12] = __uint_as_float(0x7FC00000u);   // NaN pad (excluded by both counts)
    }
    // wave min/max (fmaxf/fminf ignore NaN)
    float vmax = -1e30f, vmin = 1e30f;
#pragma unroll
    for (int i = 0; i < 13; i++) { vmax = fmaxf(vmax, sv[i]); vmin = fminf(vmin, sv[i]); }
#pragma unroll
    for (int off = 32; off > 0; off >>= 1) {
        vmax = fmaxf(vmax, __shfl_xor(vmax, off, 64));
        vmin = fminf(vmin, __shfl_xor(vmin, off, 64));
    }
    // interleaved dual bisection: thrp = TPK-th largest, thrn = TPK-th smallest
    float lo1 = vmin, hi1 = vmax, lo2 = vmin, hi2 = vmax;
    for (int it = 0; it < 15; ++it) {
        float m1 = 0.5f * (lo1 + hi1), m2 = 0.5f * (lo2 + hi2);
        int c1 = 0, c2 = 0;
#pragma unroll
        for (int i = 0; i < 13; i++) {
            c1 += __popcll(__ballot(sv[i] >= m1));
            c2 += __popcll(__ballot(sv[i] <= m2));
        }
        if (c1 >= TPK) lo1 = m1; else hi1 = m1;
        if (c2 >= TPK) hi2 = m2; else lo2 = m2;
    }
    float thrp = lo1, thrn = hi2;
    const float its = 1.0f / 0.03f;
    float spn = 0.f, spd = 0.f, snn = 0.f, snd = 0.f;
#pragma unroll
    for (int i = 0; i < 13; i++) {
        if (i == 12 && lane >= 16) continue;
        float s = sv[i];
        float mp = sigf((s - thrp) * its);
        float mn = sigf(-(s - thrn) * its);
        spn += s * mp; spd += mp;
        snn += s * mn; snd += mn;
    }
    for (int off = 32; off > 0; off >>= 1) {
        spn += __shfl_down(spn, off, 64);
        spd += __shfl_down(spd, off, 64);
        snn += __shfl_down(snn, off, 64);
        snd += __shfl_down(snd, off, 64);
    }
    if (lane == 0) {
        SP[b * B_ + d] = spn / spd;
        SN[b * B_ + d] = snn / snd;
    }
}

// ---------------------------------------------------------------- CE losses
__global__ void k_loss12(const float* __restrict__ SP, const float* __restrict__ SN,
                         float* __restrict__ acc) {
    __shared__ float red[128];
    int i = blockIdx.x, tid = threadIdx.x;
    const float itc = 1.0f / 0.07f;
    for (int phase = 0; phase < 2; phase++) {
        float mx = -INFINITY;
        for (int j = tid; j < 2 * B_; j += 128) {
            float v;
            if (phase == 0) v = (j < B_ ? SP[i * B_ + j] : SN[i * B_ + (j - B_)]);
            else            v = (j < B_ ? SP[j * B_ + i] : SN[(j - B_) * B_ + i]);
            mx = fmaxf(mx, v * itc);
        }
        red[tid] = mx; __syncthreads();
        for (int s = 64; s > 0; s >>= 1) { if (tid < s) red[tid] = fmaxf(red[tid], red[tid + s]); __syncthreads(); }
        mx = red[0]; __syncthreads();
        float se = 0.f;
        for (int j = tid; j < 2 * B_; j += 128) {
            float v;
            if (phase == 0) v = (j < B_ ? SP[i * B_ + j] : SN[i * B_ + (j - B_)]);
            else            v = (j < B_ ? SP[j * B_ + i] : SN[(j - B_) * B_ + i]);
            se += __expf(v * itc - mx);
        }
        red[tid] = se; __syncthreads();
        for (int s = 64; s > 0; s >>= 1) { if (tid < s) red[tid] += red[tid + s]; __syncthreads(); }
        if (tid == 0) {
            float lse = logf(red[0]) + mx;
            atomicAdd(&acc[phase], lse - SP[i * B_ + i] * itc);
        }
        __syncthreads();
    }
}

// ---------------------------------------------------------------- fused distance matrix
__global__ __launch_bounds__(256)
void k_distmat(const float* __restrict__ iv, const float* __restrict__ ivn,
               const float* __restrict__ fa, float* __restrict__ D) {
    __shared__ float Ai[16][68], An[16][68], Bf[16][68], Bn[16][68];
    int i0 = blockIdx.y * 64, j0 = blockIdx.x * 64;
    int tid = threadIdx.x;
    int tx = tid & 15, ty = tid >> 4;
    int r = tid >> 2, c4 = tid & 3;
    float accD[4][4], accV[4][4];
#pragma unroll
    for (int i = 0; i < 4; i++)
#pragma unroll
        for (int j = 0; j < 4; j++) { accD[i][j] = 0.f; accV[i][j] = 0.f; }

    for (int k0 = 0; k0 < C_; k0 += 16) {
        float4 v;
        v = *(const float4*)(iv + (size_t)(i0 + r) * C_ + k0 + c4 * 4);
        Ai[c4*4+0][r]=v.x; Ai[c4*4+1][r]=v.y; Ai[c4*4+2][r]=v.z; Ai[c4*4+3][r]=v.w;
        v = *(const float4*)(ivn + (size_t)(i0 + r) * C_ + k0 + c4 * 4);
        An[c4*4+0][r]=v.x; An[c4*4+1][r]=v.y; An[c4*4+2][r]=v.z; An[c4*4+3][r]=v.w;
        v = *(const float4*)(fa + (size_t)(j0 + r) * C_ + k0 + c4 * 4);
        Bf[c4*4+0][r]=v.x; Bf[c4*4+1][r]=v.y; Bf[c4*4+2][r]=v.z; Bf[c4*4+3][r]=v.w;
        v = *(const float4*)(ivn + (size_t)(j0 + r) * C_ + k0 + c4 * 4);
        Bn[c4*4+0][r]=v.x; Bn[c4*4+1][r]=v.y; Bn[c4*4+2][r]=v.z; Bn[c4*4+3][r]=v.w;
        __syncthreads();
#pragma unroll
        for (int kk = 0; kk < 16; kk++) {
            float ai[4], an[4];
#pragma unroll
            for (int i = 0; i < 4; i++) { ai[i] = Ai[kk][ty*4+i]; an[i] = An[kk][ty*4+i]; }
            float4 bf = *(const float4*)&Bf[kk][tx*4];
            float4 bn = *(const float4*)&Bn[kk][tx*4];
#pragma unroll
            for (int i = 0; i < 4; i++) {
                float d0 = ai[i] - bf.x + 1e-6f; accD[i][0] = fmaf(d0, d0, accD[i][0]);
                float d1 = ai[i] - bf.y + 1e-6f; accD[i][1] = fmaf(d1, d1, accD[i][1]);
                float d2 = ai[i] - bf.z + 1e-6f; accD[i][2] = fmaf(d2, d2, accD[i][2]);
                float d3 = ai[i] - bf.w + 1e-6f; accD[i][3] = fmaf(d3, d3, accD[i][3]);
                accV[i][0] = fmaf(an[i], bn.x, accV[i][0]);
                accV[i][1] = fmaf(an[i], bn.y, accV[i][1]);
                accV[i][2] = fmaf(an[i], bn.z, accV[i][2]);
                accV[i][3] = fmaf(an[i], bn.w, accV[i][3]);
            }
        }
        __syncthreads();
    }
#pragma unroll
    for (int i = 0; i < 4; i++)
#pragma unroll
        for (int j = 0; j < 4; j++) {
            int gi = i0 + ty * 4 + i, gj = j0 + tx * 4 + j;
            float val = (gi == gj) ? accD[i][j] : accD[i][j] * accV[i][j] * (1.0f / 191.0f);
            D[gi * B_ + gj] = val;
        }
}

// ---------------------------------------------------------------- final scalar assembly
__global__ void k_final2(const float* __restrict__ acc, const float* __restrict__ D,
                         float* __restrict__ out) {
    __shared__ float red[256];
    int tid = threadIdx.x;
    float v3 = 0.f, v4 = 0.f;
    if (tid < B_) {
        float rs = 0.f, cs = 0.f;
        for (int j = 0; j < B_; j++) rs += D[tid * B_ + j];
        for (int i = 0; i < B_; i++) cs += D[i * B_ + tid];
        v3 = fmaxf(rs + 0.6f, 0.f);
        v4 = fmaxf(cs + 0.6f, 0.f);
    }
    red[tid] = v3; __syncthreads();
    for (int s = 128; s > 0; s >>= 1) { if (tid < s) red[tid] += red[tid + s]; __syncthreads(); }
    float l3 = red[0] / B_;
    __syncthreads();
    red[tid] = v4; __syncthreads();
    for (int s = 128; s > 0; s >>= 1) { if (tid < s) red[tid] += red[tid + s]; __syncthreads(); }
    float l4 = red[0] / B_;
    if (tid == 0) {
        out[0] = 0.5f * (acc[0] + acc[1]) / B_;
        out[1] = 0.5f * (l3 + l4);
    }
}

extern "C" void kernel_launch(void* const* d_in, const int* in_sizes, int n_in,
                              void* d_out, int out_size, void* d_ws, size_t ws_size,
                              hipStream_t stream) {
    const float* ev  = (const float*)d_in[0];
    const float* ea  = (const float*)d_in[1];
    const float* Wv  = (const float*)d_in[2];
    const float* Wa1 = (const float*)d_in[3];
    const float* Wa2 = (const float*)d_in[4];
    float* out = (float*)d_out;
    float* ws  = (float*)d_ws;

    size_t off = 0;
    float* evmean  = ws + off; off += B_ * C_;
    float* ind_vec = ws + off; off += B_ * C_;
    float* iv_norm = ws + off; off += B_ * C_;
    float* fa      = ws + off; off += B_ * C_;
    float* Hb      = ws + off; off += B_ * C_;
    float* n2      = ws + off; off += B_ * HW_;
    float* SPb     = ws + off; off += B_ * B_;
    float* SNb     = ws + off; off += B_ * B_;
    float* Db      = ws + off; off += B_ * B_;
    float* accb    = ws + off; off += 16;
    unsigned short* Abf = (unsigned short*)(ws + off); off += 768 * C_ / 2;

    size_t perB_f = (size_t)PPAD * C_ / 2 + (size_t)B_ * HW_ / 2;
    size_t avail  = ws_size / 4 > off ? ws_size / 4 - off : 0;
    int chunk = (int)(avail / perB_f);
    if (chunk > B_) chunk = B_;
    if (chunk < 1) chunk = 1;
    unsigned short* evT = (unsigned short*)(ws + off);
    unsigned short* Tb  = evT + (size_t)chunk * PPAD * C_;

    hipMemsetAsync(n2,   0, B_ * HW_ * sizeof(float), stream);
    hipMemsetAsync(accb, 0, 2 * sizeof(float), stream);

    dim3 g24(C_ / 64, B_ / 64);   // N=512, M=192

    // Abf rows 0..511 (Wv) + zero pad rows 704..767 — independent, do first
    k_prepA<<<576, 256, 0, stream>>>(Wv, Abf);

    if (chunk >= B_) {
        hipMemsetAsync(evmean, 0, B_ * C_ * sizeof(float), stream);
        dim3 gt(PPAD / 64, C_ / 64, B_);
        k_transpose64<<<gt, 256, 0, stream>>>(ev, evT, evmean, 1, 0);
    } else {
        k_evmean<<<B_ * C_ / 4, 256, 0, stream>>>(ev, evmean);
    }

    // visual projection chain
    k32<0, 0, 0><<<g24, 256, 0, stream>>>(evmean, Wv, ind_vec, B_, C_, C_);
    k_rownorm<<<B_, 64, 0, stream>>>(ind_vec, iv_norm);
    k32<1, 0, 1><<<g24, 256, 0, stream>>>(iv_norm, Wv, Abf + (size_t)512 * C_, B_, C_, C_);

    // audio chain
    k32<0, 1, 0><<<g24, 256, 0, stream>>>(ea, Wa1, Hb, B_, C_, 2048);
    k32<0, 0, 0><<<g24, 256, 0, stream>>>(Hb, Wa2, fa, B_, C_, C_);

    if (chunk >= B_) {
        // split gemm into two 96-batch dispatches (diagnostic: surfaces #2 kernel in top-5)
        int grid96 = 8 * ((96 * 42 + 7) / 8);
        k_gemm<<<grid96, 256, 0, stream>>>(Abf, evT, n2, Tb, 0, 96);
        k_gemm<<<grid96, 256, 0, stream>>>(Abf, evT + (size_t)96 * PPAD * C_, n2,
                                           Tb + (size_t)96 * B_ * HW_, 96, 96);
        dim3 gp(B_ / 4, B_);
        k_pool<<<gp, 256, 0, stream>>>(Tb, n2, SPb, SNb, 0);
    } else {
        for (int b0 = 0; b0 < B_; b0 += chunk) {
            int nb = (B_ - b0 < chunk) ? (B_ - b0) : chunk;
            dim3 gt(PPAD / 64, C_ / 64, nb);
            k_transpose64<<<gt, 256, 0, stream>>>(ev, evT, evmean, 0, b0);
            int grid = 8 * ((nb * 42 + 7) / 8);
            k_gemm<<<grid, 256, 0, stream>>>(Abf, evT, n2, Tb, b0, nb);
            dim3 gp(B_ / 4, nb);
            k_pool<<<gp, 256, 0, stream>>>(Tb, n2, SPb, SNb, b0);
        }
    }

    k_loss12<<<B_, 128, 0, stream>>>(SPb, SNb, accb);
    dim3 gd(B_ / 64, B_ / 64);
    k_distmat<<<gd, 256, 0, stream>>>(ind_vec, iv_norm, fa, Db);
    k_final2<<<1, 256, 0, stream>>>(accb, Db, out);
}

// Round 6
// 575.436 us; speedup vs baseline: 4.4239x; 1.1988x over previous
//
#include <hip/hip_runtime.h>
#include <math.h>

#define B_   192
#define C_   512
#define HW_  784
#define TPK  23          // int(784*0.03)
#define PPAD 896         // 7 p-tiles of 128

typedef __attribute__((ext_vector_type(8))) short s8bf;
typedef __attribute__((ext_vector_type(4))) float f4;
typedef __attribute__((ext_vector_type(8))) unsigned short us8;

__device__ __forceinline__ float sigf(float x) {
    return 1.0f / (1.0f + __expf(-x));
}
__device__ __forceinline__ unsigned short f2bf(float f) {
    unsigned u = __float_as_uint(f);
    unsigned r = u + 0x7FFFu + ((u >> 16) & 1u);
    return (unsigned short)(r >> 16);
}
__device__ __forceinline__ float bf2f(unsigned short u) {
    return __uint_as_float(((unsigned)u) << 16);
}
__device__ __forceinline__ void gld16(const unsigned short* g, unsigned short* l) {
    __builtin_amdgcn_global_load_lds((const __attribute__((address_space(1))) unsigned int*)g,
                                     (__attribute__((address_space(3))) unsigned int*)l, 16, 0, 0);
}

// ---------------------------------------------------------------- evmean (fallback only)
__global__ void k_evmean(const float* __restrict__ ev, float* __restrict__ evmean) {
    int row  = blockIdx.x * 4 + (threadIdx.x >> 6);
    int lane = threadIdx.x & 63;
    const float4* s4 = (const float4*)(ev + (size_t)row * HW_);
    float s = 0.f;
    for (int i = lane; i < HW_ / 4; i += 64) {
        float4 v = s4[i];
        s += v.x + v.y + v.z + v.w;
    }
    for (int off = 32; off > 0; off >>= 1) s += __shfl_down(s, off, 64);
    if (lane == 0) evmean[row] = s * (1.0f / HW_);
}

// ---------------------------------------------------------------- tiled fp32 GEMM w/ split-K
// BKN=0: B[N][K] (B^T), BKN=1: B[K][N]. RELUA: relu on A-load.
// SPLITK>1: z-sliced K, atomicAdd into pre-zeroed C (fp32 only).
template<int BKN, int RELUA, int BF16OUT, int SPLITK>
__global__ __launch_bounds__(256)
void k32(const float* __restrict__ A, const float* __restrict__ B,
         void* __restrict__ Cv, int M, int N, int K) {
    __shared__ float As[16][68];
    __shared__ float Bs[16][68];
    int m0 = blockIdx.y * 64, n0 = blockIdx.x * 64;
    int kslice = K / SPLITK;
    int kbeg = blockIdx.z * kslice;
    int tid = threadIdx.x;
    int tx = tid & 15, ty = tid >> 4;
    int r = tid >> 2, c4 = tid & 3;

    float acc[4][4];
#pragma unroll
    for (int i = 0; i < 4; i++)
#pragma unroll
        for (int j = 0; j < 4; j++) acc[i][j] = 0.f;

    for (int k0 = kbeg; k0 < kbeg + kslice; k0 += 16) {
        float4 av = *(const float4*)(A + (size_t)(m0 + r) * K + k0 + c4 * 4);
        if (RELUA) {
            av.x = fmaxf(av.x, 0.f); av.y = fmaxf(av.y, 0.f);
            av.z = fmaxf(av.z, 0.f); av.w = fmaxf(av.w, 0.f);
        }
        As[c4 * 4 + 0][r] = av.x; As[c4 * 4 + 1][r] = av.y;
        As[c4 * 4 + 2][r] = av.z; As[c4 * 4 + 3][r] = av.w;
        if (BKN == 0) {
            float4 bv = *(const float4*)(B + (size_t)(n0 + r) * K + k0 + c4 * 4);
            Bs[c4 * 4 + 0][r] = bv.x; Bs[c4 * 4 + 1][r] = bv.y;
            Bs[c4 * 4 + 2][r] = bv.z; Bs[c4 * 4 + 3][r] = bv.w;
        } else {
            float4 bv = *(const float4*)(B + (size_t)(k0 + ty) * N + n0 + tx * 4);
            Bs[ty][tx * 4 + 0] = bv.x; Bs[ty][tx * 4 + 1] = bv.y;
            Bs[ty][tx * 4 + 2] = bv.z; Bs[ty][tx * 4 + 3] = bv.w;
        }
        __syncthreads();
#pragma unroll
        for (int kk = 0; kk < 16; kk++) {
            float a_[4];
#pragma unroll
            for (int i = 0; i < 4; i++) a_[i] = As[kk][ty * 4 + i];
            float4 bb = *(const float4*)&Bs[kk][tx * 4];
#pragma unroll
            for (int i = 0; i < 4; i++) {
                acc[i][0] = fmaf(a_[i], bb.x, acc[i][0]);
                acc[i][1] = fmaf(a_[i], bb.y, acc[i][1]);
                acc[i][2] = fmaf(a_[i], bb.z, acc[i][2]);
                acc[i][3] = fmaf(a_[i], bb.w, acc[i][3]);
            }
        }
        __syncthreads();
    }
#pragma unroll
    for (int i = 0; i < 4; i++) {
        if (SPLITK > 1) {
            float* C = (float*)Cv;
            float* row = C + (size_t)(m0 + ty * 4 + i) * N + n0 + tx * 4;
#pragma unroll
            for (int j = 0; j < 4; j++) atomicAdd(&row[j], acc[i][j]);
        } else if (BF16OUT) {
            unsigned short* C16 = (unsigned short*)Cv;
            ushort4 o;
            o.x = f2bf(acc[i][0]); o.y = f2bf(acc[i][1]);
            o.z = f2bf(acc[i][2]); o.w = f2bf(acc[i][3]);
            *(ushort4*)(C16 + (size_t)(m0 + ty * 4 + i) * N + n0 + tx * 4) = o;
        } else {
            float* C = (float*)Cv;
            *(float4*)(C + (size_t)(m0 + ty * 4 + i) * N + n0 + tx * 4) =
                make_float4(acc[i][0], acc[i][1], acc[i][2], acc[i][3]);
        }
    }
}

// ---------------------------------------------------------------- iv_norm = l2norm(ind_vec) per row
__global__ void k_rownorm(const float* __restrict__ iv, float* __restrict__ ivn) {
    int b = blockIdx.x, lane = threadIdx.x;
    float v[8]; float s = 0.f;
#pragma unroll
    for (int k = 0; k < 8; k++) {
        v[k] = iv[(size_t)b * C_ + lane + 64 * k];
        s = fmaf(v[k], v[k], s);
    }
#pragma unroll
    for (int off = 32; off > 0; off >>= 1) s += __shfl_xor(s, off, 64);
    float rn = 1.0f / fmaxf(sqrtf(s), 1e-12f);
#pragma unroll
    for (int k = 0; k < 8; k++) ivn[(size_t)b * C_ + lane + 64 * k] = v[k] * rn;
}

// ---------------------------------------------------------------- Abf rows 0..511 = bf16(Wv), rows 704..767 = 0
__global__ void k_prepA(const float* __restrict__ Wv, unsigned short* __restrict__ Abf) {
    int r = blockIdx.x, tid = threadIdx.x;
    int row = (r < 512) ? r : (192 + r);   // 512..575 -> 704..767 zero pad
    for (int i = 0; i < 2; i++) {
        int c = tid + i * 256;
        float v = (r < 512) ? Wv[(size_t)r * C_ + c] : 0.f;
        Abf[(size_t)row * C_ + c] = f2bf(v);
    }
}

// ---------------------------------------------------------------- ev[b][c][p] fp32 -> evT[bl][p][c] bf16 (64x64 tiles)
__global__ __launch_bounds__(256)
void k_transpose64(const float* __restrict__ ev, unsigned short* __restrict__ evT,
                   float* __restrict__ evsum, int doevm, int b0) {
    __shared__ float t[64][67];   // pad 67: read stride 8*67=536 -> bank step 6, conflict-free
    int bl = blockIdx.z, b = b0 + bl;
    int c0 = blockIdx.y * 64, p0 = blockIdx.x * 64;
    int tid = threadIdx.x;
    int cl = tid >> 4;
    int pc = tid & 15;
    int p = p0 + pc * 4;
#pragma unroll
    for (int q = 0; q < 4; q++) {
        int c_local = q * 16 + cl;
        const float* src = ev + ((size_t)b * C_ + c0 + c_local) * HW_;
        float4 v = make_float4(0.f, 0.f, 0.f, 0.f);
        if (p + 3 < HW_) v = *(const float4*)(src + p);
        else if (p < HW_) { for (int j = 0; j < 4; j++) if (p + j < HW_) ((float*)&v)[j] = src[p + j]; }
        if (doevm) {
            float rs = v.x + v.y + v.z + v.w;
            rs += __shfl_xor(rs, 1, 16);
            rs += __shfl_xor(rs, 2, 16);
            rs += __shfl_xor(rs, 4, 16);
            rs += __shfl_xor(rs, 8, 16);
            if (pc == 0) atomicAdd(&evsum[b * C_ + c0 + c_local], rs * (1.0f / HW_));
        }
        t[c_local][pc * 4 + 0] = v.x; t[c_local][pc * 4 + 1] = v.y;
        t[c_local][pc * 4 + 2] = v.z; t[c_local][pc * 4 + 3] = v.w;
    }
    __syncthreads();
    int r = tid >> 3;   // 0..31 p-row
    int j = tid & 7;    // c-chunk of 8
#pragma unroll
    for (int q = 0; q < 2; q++) {
        int row = r + q * 32;
        us8 o;
#pragma unroll
        for (int k = 0; k < 8; k++) o[k] = f2bf(t[j * 8 + k][row]);
        *(us8*)(evT + ((size_t)bl * PPAD + p0 + row) * C_ + c0 + j * 8) = o;
    }
}

// ---------------------------------------------------------------- MFMA GEMM: [Wv;U](704x512) @ ev[b](512x784)
__global__ __launch_bounds__(256, 4)
void k_gemm(const unsigned short* __restrict__ Abf, const unsigned short* __restrict__ evT,
            float* __restrict__ n2, unsigned short* __restrict__ Tb, int b0, int nb) {
    __shared__ unsigned short As[2][4096];   // [128][32]
    __shared__ unsigned short Bs[2][4096];   // [128][32]

    int id = blockIdx.x;
    int xcd = id & 7, slot = id >> 3;
    int S = (nb * 42 + 7) >> 3;
    int w = xcd * S + slot;
    if (w >= nb * 42) return;
    int bl = w / 42, rem = w % 42;
    int pt = rem / 6, ot = rem % 6;
    int o0 = ot * 128, p0 = pt * 128;

    int tid = threadIdx.x;
    int wid = tid >> 6, lane = tid & 63;
    int wy = wid >> 1, wx = wid & 1;
    int l15 = lane & 15, l4 = lane >> 4;

    const unsigned short* Ag = Abf + ((size_t)o0 + (tid >> 2)) * C_ + (tid & 3) * 8;
    const unsigned short* Bg = evT + ((size_t)bl * PPAD + p0 + (tid >> 2)) * C_ + (tid & 3) * 8;
    int lds_off = wid * 512 + lane * 8;

    f4 acc[4][4] = {};
    int cur = 0;

#define STAGE(buf, k0) do { \
    gld16(Ag + (k0),             &As[buf][0] + lds_off); \
    gld16(Ag + (k0) + 64 * C_,   &As[buf][2048] + lds_off); \
    gld16(Bg + (k0),             &Bs[buf][0] + lds_off); \
    gld16(Bg + (k0) + 64 * C_,   &Bs[buf][2048] + lds_off); \
} while (0)

    STAGE(0, 0);
    __syncthreads();
    for (int t = 0; t < 16; ++t) {
        if (t < 15) STAGE(cur ^ 1, (t + 1) * 32);
        const s8bf* Ar = (const s8bf*)&As[cur][0];
        const s8bf* Br = (const s8bf*)&Bs[cur][0];
        s8bf a[4], b[4];
#pragma unroll
        for (int mi = 0; mi < 4; mi++) a[mi] = Ar[(wy * 64 + mi * 16 + l15) * 4 + l4];
#pragma unroll
        for (int ni = 0; ni < 4; ni++) b[ni] = Br[(wx * 64 + ni * 16 + l15) * 4 + l4];
#pragma unroll
        for (int mi = 0; mi < 4; mi++)
#pragma unroll
            for (int ni = 0; ni < 4; ni++)
                acc[mi][ni] = __builtin_amdgcn_mfma_f32_16x16x32_bf16(a[mi], b[ni], acc[mi][ni], 0, 0, 0);
        __syncthreads();
        cur ^= 1;
    }
#undef STAGE

    if (ot < 4) {
        float* red = (float*)&As[0][0];
#pragma unroll
        for (int ni = 0; ni < 4; ni++) {
            float s = 0.f;
#pragma unroll
            for (int mi = 0; mi < 4; mi++)
#pragma unroll
                for (int r = 0; r < 4; r++) { float x = acc[mi][ni][r]; s = fmaf(x, x, s); }
            red[(wy * 4 + l4) * 128 + wx * 64 + ni * 16 + l15] = s;
        }
        __syncthreads();
        if (tid < 128) {
            float s = 0.f;
#pragma unroll
            for (int q = 0; q < 8; q++) s += red[q * 128 + tid];
            int p = p0 + tid;
            if (p < HW_) atomicAdd(&n2[(size_t)(b0 + bl) * HW_ + p], s);
        }
    } else {
        int dbase = o0 - 512 + wy * 64;
#pragma unroll
        for (int mi = 0; mi < 4; mi++)
#pragma unroll
            for (int r = 0; r < 4; r++) {
                int dd = dbase + mi * 16 + l4 * 4 + r;
                if (dd < B_) {
                    size_t rowoff = ((size_t)bl * B_ + dd) * HW_;
#pragma unroll
                    for (int ni = 0; ni < 4; ni++) {
                        int p = p0 + wx * 64 + ni * 16 + l15;
                        if (p < HW_) Tb[rowoff + p] = f2bf(acc[mi][ni][r]);
                    }
                }
            }
    }
}

// ---------------------------------------------------------------- pool: wave per (b,d); dual interleaved bisection
__global__ __launch_bounds__(256)
void k_pool(const unsigned short* __restrict__ T, const float* __restrict__ n2,
            float* __restrict__ SP, float* __restrict__ SN, int b0) {
    int tid = threadIdx.x;
    int wv = tid >> 6, lane = tid & 63;
    int d = blockIdx.x * 4 + wv;
    int bl = blockIdx.y, b = b0 + bl;
    const unsigned short* Trow = T + ((size_t)bl * B_ + d) * HW_;
    const float* nrow = n2 + (size_t)b * HW_;
    float sv[13];
#pragma unroll
    for (int i = 0; i < 12; i++) {
        int p = lane + i * 64;
        float nv = fmaxf(sqrtf(nrow[p]), 1e-12f);
        sv[i] = bf2f(Trow[p]) / nv;
    }
    {
        int p = lane + 768;
        if (p < HW_) {
            float nv = fmaxf(sqrtf(nrow[p]), 1e-12f);
            sv[12] = bf2f(Trow[p]) / nv;
        } else sv[12] = __uint_as_float(0x7FC00000u);   // NaN pad
    }
    float vmax = -1e30f, vmin = 1e30f;
#pragma unroll
    for (int i = 0; i < 13; i++) { vmax = fmaxf(vmax, sv[i]); vmin = fminf(vmin, sv[i]); }
#pragma unroll
    for (int off = 32; off > 0; off >>= 1) {
        vmax = fmaxf(vmax, __shfl_xor(vmax, off, 64));
        vmin = fminf(vmin, __shfl_xor(vmin, off, 64));
    }
    float lo1 = vmin, hi1 = vmax, lo2 = vmin, hi2 = vmax;
    for (int it = 0; it < 15; ++it) {
        float m1 = 0.5f * (lo1 + hi1), m2 = 0.5f * (lo2 + hi2);
        int c1 = 0, c2 = 0;
#pragma unroll
        for (int i = 0; i < 13; i++) {
            c1 += __popcll(__ballot(sv[i] >= m1));
            c2 += __popcll(__ballot(sv[i] <= m2));
        }
        if (c1 >= TPK) lo1 = m1; else hi1 = m1;
        if (c2 >= TPK) hi2 = m2; else lo2 = m2;
    }
    float thrp = lo1, thrn = hi2;
    const float its = 1.0f / 0.03f;
    float spn = 0.f, spd = 0.f, snn = 0.f, snd = 0.f;
#pragma unroll
    for (int i = 0; i < 13; i++) {
        if (i == 12 && lane >= 16) continue;
        float s = sv[i];
        float mp = sigf((s - thrp) * its);
        float mn = sigf(-(s - thrn) * its);
        spn += s * mp; spd += mp;
        snn += s * mn; snd += mn;
    }
    for (int off = 32; off > 0; off >>= 1) {
        spn += __shfl_down(spn, off, 64);
        spd += __shfl_down(spd, off, 64);
        snn += __shfl_down(snn, off, 64);
        snd += __shfl_down(snd, off, 64);
    }
    if (lane == 0) {
        SP[b * B_ + d] = spn / spd;
        SN[b * B_ + d] = snn / snd;
    }
}

// ---------------------------------------------------------------- CE losses
__global__ void k_loss12(const float* __restrict__ SP, const float* __restrict__ SN,
                         float* __restrict__ acc) {
    __shared__ float red[128];
    int i = blockIdx.x, tid = threadIdx.x;
    const float itc = 1.0f / 0.07f;
    for (int phase = 0; phase < 2; phase++) {
        float mx = -INFINITY;
        for (int j = tid; j < 2 * B_; j += 128) {
            float v;
            if (phase == 0) v = (j < B_ ? SP[i * B_ + j] : SN[i * B_ + (j - B_)]);
            else            v = (j < B_ ? SP[j * B_ + i] : SN[(j - B_) * B_ + i]);
            mx = fmaxf(mx, v * itc);
        }
        red[tid] = mx; __syncthreads();
        for (int s = 64; s > 0; s >>= 1) { if (tid < s) red[tid] = fmaxf(red[tid], red[tid + s]); __syncthreads(); }
        mx = red[0]; __syncthreads();
        float se = 0.f;
        for (int j = tid; j < 2 * B_; j += 128) {
            float v;
            if (phase == 0) v = (j < B_ ? SP[i * B_ + j] : SN[i * B_ + (j - B_)]);
            else            v = (j < B_ ? SP[j * B_ + i] : SN[(j - B_) * B_ + i]);
            se += __expf(v * itc - mx);
        }
        red[tid] = se; __syncthreads();
        for (int s = 64; s > 0; s >>= 1) { if (tid < s) red[tid] += red[tid + s]; __syncthreads(); }
        if (tid == 0) {
            float lse = logf(red[0]) + mx;
            atomicAdd(&acc[phase], lse - SP[i * B_ + i] * itc);
        }
        __syncthreads();
    }
}

// ---------------------------------------------------------------- fused distance matrix + rowsum/colsum + final (last block)
__global__ __launch_bounds__(256)
void k_distfin(const float* __restrict__ iv, const float* __restrict__ ivn,
               const float* __restrict__ fa, const float* __restrict__ acc,
               float* __restrict__ rowsum, float* __restrict__ colsum,
               int* __restrict__ cnt, float* __restrict__ out) {
    __shared__ float Ai[16][68], An[16][68], Bf[16][68], Bn[16][68];
    __shared__ float rred[64][17], cred[64][17];
    __shared__ float fr[256];
    __shared__ int lastf;
    int i0 = blockIdx.y * 64, j0 = blockIdx.x * 64;
    int tid = threadIdx.x;
    int tx = tid & 15, ty = tid >> 4;
    int r = tid >> 2, c4 = tid & 3;
    float accD[4][4], accV[4][4];
#pragma unroll
    for (int i = 0; i < 4; i++)
#pragma unroll
        for (int j = 0; j < 4; j++) { accD[i][j] = 0.f; accV[i][j] = 0.f; }

    for (int k0 = 0; k0 < C_; k0 += 16) {
        float4 v;
        v = *(const float4*)(iv + (size_t)(i0 + r) * C_ + k0 + c4 * 4);
        Ai[c4*4+0][r]=v.x; Ai[c4*4+1][r]=v.y; Ai[c4*4+2][r]=v.z; Ai[c4*4+3][r]=v.w;
        v = *(const float4*)(ivn + (size_t)(i0 + r) * C_ + k0 + c4 * 4);
        An[c4*4+0][r]=v.x; An[c4*4+1][r]=v.y; An[c4*4+2][r]=v.z; An[c4*4+3][r]=v.w;
        v = *(const float4*)(fa + (size_t)(j0 + r) * C_ + k0 + c4 * 4);
        Bf[c4*4+0][r]=v.x; Bf[c4*4+1][r]=v.y; Bf[c4*4+2][r]=v.z; Bf[c4*4+3][r]=v.w;
        v = *(const float4*)(ivn + (size_t)(j0 + r) * C_ + k0 + c4 * 4);
        Bn[c4*4+0][r]=v.x; Bn[c4*4+1][r]=v.y; Bn[c4*4+2][r]=v.z; Bn[c4*4+3][r]=v.w;
        __syncthreads();
#pragma unroll
        for (int kk = 0; kk < 16; kk++) {
            float ai[4], an[4];
#pragma unroll
            for (int i = 0; i < 4; i++) { ai[i] = Ai[kk][ty*4+i]; an[i] = An[kk][ty*4+i]; }
            float4 bf = *(const float4*)&Bf[kk][tx*4];
            float4 bn = *(const float4*)&Bn[kk][tx*4];
#pragma unroll
            for (int i = 0; i < 4; i++) {
                float d0 = ai[i] - bf.x + 1e-6f; accD[i][0] = fmaf(d0, d0, accD[i][0]);
                float d1 = ai[i] - bf.y + 1e-6f; accD[i][1] = fmaf(d1, d1, accD[i][1]);
                float d2 = ai[i] - bf.z + 1e-6f; accD[i][2] = fmaf(d2, d2, accD[i][2]);
                float d3 = ai[i] - bf.w + 1e-6f; accD[i][3] = fmaf(d3, d3, accD[i][3]);
                accV[i][0] = fmaf(an[i], bn.x, accV[i][0]);
                accV[i][1] = fmaf(an[i], bn.y, accV[i][1]);
                accV[i][2] = fmaf(an[i], bn.z, accV[i][2]);
                accV[i][3] = fmaf(an[i], bn.w, accV[i][3]);
            }
        }
        __syncthreads();
    }
    float rp[4] = {0.f, 0.f, 0.f, 0.f};
    float cp[4] = {0.f, 0.f, 0.f, 0.f};
#pragma unroll
    for (int i = 0; i < 4; i++)
#pragma unroll
        for (int j = 0; j < 4; j++) {
            int gi = i0 + ty * 4 + i, gj = j0 + tx * 4 + j;
            float val = (gi == gj) ? accD[i][j] : accD[i][j] * accV[i][j] * (1.0f / 191.0f);
            rp[i] += val; cp[j] += val;
        }
#pragma unroll
    for (int i = 0; i < 4; i++) rred[ty * 4 + i][tx] = rp[i];
#pragma unroll
    for (int j = 0; j < 4; j++) cred[tx * 4 + j][ty] = cp[j];
    __syncthreads();
    if (tid < 64) {
        float s = 0.f;
#pragma unroll
        for (int q = 0; q < 16; q++) s += rred[tid][q];
        atomicAdd(&rowsum[i0 + tid], s);
    } else if (tid < 128) {
        int t = tid - 64;
        float s = 0.f;
#pragma unroll
        for (int q = 0; q < 16; q++) s += cred[t][q];
        atomicAdd(&colsum[j0 + t], s);
    }
    __threadfence();
    __syncthreads();
    if (tid == 0) lastf = (atomicAdd(cnt, 1) == 8);
    __syncthreads();
    if (lastf) {
        __threadfence();
        float v3 = (tid < B_) ? fmaxf(rowsum[tid] + 0.6f, 0.f) : 0.f;
        float v4 = (tid < B_) ? fmaxf(colsum[tid] + 0.6f, 0.f) : 0.f;
        fr[tid] = v3; __syncthreads();
        for (int s = 128; s > 0; s >>= 1) { if (tid < s) fr[tid] += fr[tid + s]; __syncthreads(); }
        float l3 = fr[0] / B_;
        __syncthreads();
        fr[tid] = v4; __syncthreads();
        for (int s = 128; s > 0; s >>= 1) { if (tid < s) fr[tid] += fr[tid + s]; __syncthreads(); }
        float l4 = fr[0] / B_;
        if (tid == 0) {
            out[0] = 0.5f * (acc[0] + acc[1]) / B_;
            out[1] = 0.5f * (l3 + l4);
        }
    }
}

extern "C" void kernel_launch(void* const* d_in, const int* in_sizes, int n_in,
                              void* d_out, int out_size, void* d_ws, size_t ws_size,
                              hipStream_t stream) {
    const float* ev  = (const float*)d_in[0];
    const float* ea  = (const float*)d_in[1];
    const float* Wv  = (const float*)d_in[2];
    const float* Wa1 = (const float*)d_in[3];
    const float* Wa2 = (const float*)d_in[4];
    float* out = (float*)d_out;
    float* ws  = (float*)d_ws;

    size_t off = 0;
    // contiguous zero-block 1: evmean, ind_vec, Hb, fa (split-K atomic targets + evmean)
    float* evmean  = ws + off; off += B_ * C_;
    float* ind_vec = ws + off; off += B_ * C_;
    float* Hb      = ws + off; off += B_ * C_;
    float* fa      = ws + off; off += B_ * C_;
    float* iv_norm = ws + off; off += B_ * C_;
    float* n2      = ws + off; off += B_ * HW_;
    float* SPb     = ws + off; off += B_ * B_;
    float* SNb     = ws + off; off += B_ * B_;
    // contiguous zero-block 2: acc(16), rowsum(192), colsum(192), cnt(+pad)
    float* accb    = ws + off;
    float* rowsum  = accb + 16;
    float* colsum  = rowsum + B_;
    int*   cntp    = (int*)(colsum + B_);
    off += 16 + B_ + B_ + 16;
    unsigned short* Abf = (unsigned short*)(ws + off); off += 768 * C_ / 2;

    size_t perB_f = (size_t)PPAD * C_ / 2 + (size_t)B_ * HW_ / 2;
    size_t avail  = ws_size / 4 > off ? ws_size / 4 - off : 0;
    int chunk = (int)(avail / perB_f);
    if (chunk > B_) chunk = B_;
    if (chunk < 1) chunk = 1;
    unsigned short* evT = (unsigned short*)(ws + off);
    unsigned short* Tb  = evT + (size_t)chunk * PPAD * C_;

    hipMemsetAsync(evmean, 0, 4 * B_ * C_ * sizeof(float), stream);      // evmean..fa
    hipMemsetAsync(n2,     0, B_ * HW_ * sizeof(float), stream);
    hipMemsetAsync(accb,   0, (16 + 2 * B_ + 16) * sizeof(float), stream);

    k_prepA<<<576, 256, 0, stream>>>(Wv, Abf);

    if (chunk >= B_) {
        dim3 gt(PPAD / 64, C_ / 64, B_);
        k_transpose64<<<gt, 256, 0, stream>>>(ev, evT, evmean, 1, 0);
    } else {
        k_evmean<<<B_ * C_ / 4, 256, 0, stream>>>(ev, evmean);
    }

    // audio chain (independent of transpose; split-K for occupancy)
    k32<0, 0, 0, 4><<<dim3(8, 3, 4), 256, 0, stream>>>(ea, Wa1, Hb, B_, C_, 2048);
    k32<0, 1, 0, 2><<<dim3(8, 3, 2), 256, 0, stream>>>(Hb, Wa2, fa, B_, C_, C_);

    // visual chain
    k32<0, 0, 0, 2><<<dim3(8, 3, 2), 256, 0, stream>>>(evmean, Wv, ind_vec, B_, C_, C_);
    k_rownorm<<<B_, 64, 0, stream>>>(ind_vec, iv_norm);
    k32<1, 0, 1, 1><<<dim3(8, 3, 1), 256, 0, stream>>>(iv_norm, Wv, Abf + (size_t)512 * C_, B_, C_, C_);

    if (chunk >= B_) {
        int grid = 8 * ((B_ * 42 + 7) / 8);
        k_gemm<<<grid, 256, 0, stream>>>(Abf, evT, n2, Tb, 0, B_);
        dim3 gp(B_ / 4, B_);
        k_pool<<<gp, 256, 0, stream>>>(Tb, n2, SPb, SNb, 0);
    } else {
        for (int b0 = 0; b0 < B_; b0 += chunk) {
            int nb = (B_ - b0 < chunk) ? (B_ - b0) : chunk;
            dim3 gt(PPAD / 64, C_ / 64, nb);
            k_transpose64<<<gt, 256, 0, stream>>>(ev, evT, evmean, 0, b0);
            int grid = 8 * ((nb * 42 + 7) / 8);
            k_gemm<<<grid, 256, 0, stream>>>(Abf, evT, n2, Tb, b0, nb);
            dim3 gp(B_ / 4, nb);
            k_pool<<<gp, 256, 0, stream>>>(Tb, n2, SPb, SNb, b0);
        }
    }

    k_loss12<<<B_, 128, 0, stream>>>(SPb, SNb, accb);
    dim3 gd(B_ / 64, B_ / 64);
    k_distfin<<<gd, 256, 0, stream>>>(ind_vec, iv_norm, fa, accb, rowsum, colsum, cntp, out);
}